// Round 19
// baseline (136.047 us; speedup 1.0000x reference)
//
#include <hip/hip_runtime.h>
#include <hip/hip_bf16.h>
#include <math.h>

// ---------------------------------------------------------------------------
// M=30000 nodes, S=8 cells, D=32 channels, DEPTH_LIMIT=10, H=64, L=7M+1.
// 4 nodes: zero(gcnt) -> prep -> conv -> mlp.
// Round-19: conv rewritten QUARTER-PARALLEL: each 16-lane quarter owns one
// run (lane16 = og4*4+ig4 -> 8 out-chans x 8 in-chans). The 4 runs' serial
// step chains now advance concurrently (wave-serial steps = max, not sum),
// block state removed (ov reloads from L1, dups are adjacent-only), and
// launch_bounds(256,8) doubles co-residency. Attribution (r16/r18): conv
// 23.5us was serial-chain latency at 1.6 waves/SIMD.
// ---------------------------------------------------------------------------

typedef __attribute__((ext_vector_type(8))) short short8;
typedef __attribute__((ext_vector_type(4))) float f32x4;

#define WT_N 81920    // 10*32*32*8
#define RCAP 30720    // per-depth run-list capacity
#define RSTRIDE 32    // gcnt padding (ints): one counter per 128B line
#define FSLOTS 256    // feats_part rows (one 128B line each)

__device__ __forceinline__ unsigned short f2bf(float x) {
    __hip_bfloat16 h = __float2bfloat16(x);
    return *reinterpret_cast<unsigned short*>(&h);
}
__device__ __forceinline__ float bf2f(unsigned short h) {
    union { float f; unsigned u; } v; v.u = ((unsigned)h) << 16;
    return v.f;
}

__device__ __forceinline__ float4 shfl4(float4 v, int src) {
    float4 r;
    r.x = __shfl(v.x, src, 64);
    r.y = __shfl(v.y, src, 64);
    r.z = __shfl(v.z, src, 64);
    r.w = __shfl(v.w, src, 64);
    return r;
}

// reduce 8 floats (2 float4) over lane bits 0-1 (ig4)
__device__ __forceinline__ void red_ig4(float4& A, float4& B) {
    #pragma unroll
    for (int m = 1; m <= 2; m <<= 1) {
        A.x += __shfl_xor(A.x, m, 64); A.y += __shfl_xor(A.y, m, 64);
        A.z += __shfl_xor(A.z, m, 64); A.w += __shfl_xor(A.w, m, 64);
        B.x += __shfl_xor(B.x, m, 64); B.y += __shfl_xor(B.y, m, 64);
        B.z += __shfl_xor(B.z, m, 64); B.w += __shfl_xor(B.w, m, 64);
    }
}

// reduce 8 floats over lane bits 4-5 (quarter)
__device__ __forceinline__ void red_q(float4& A, float4& B) {
    #pragma unroll
    for (int m = 16; m <= 32; m <<= 1) {
        A.x += __shfl_xor(A.x, m, 64); A.y += __shfl_xor(A.y, m, 64);
        A.z += __shfl_xor(A.z, m, 64); A.w += __shfl_xor(A.w, m, 64);
        B.x += __shfl_xor(B.x, m, 64); B.y += __shfl_xor(B.y, m, 64);
        B.z += __shfl_xor(B.z, m, 64); B.w += __shfl_xor(B.w, m, 64);
    }
}

__device__ __forceinline__ float gelu_fast(float x)
{
    float e = __expf(-1.702f * x);
    return x * __builtin_amdgcn_rcpf(1.0f + e);
}

// Kernel Z: zero gcnt.
__global__ __launch_bounds__(256) void zero_kernel(int* __restrict__ dst)
{
    int i = blockIdx.x * 256 + threadIdx.x;
    if (i < 10 * RSTRIDE) dst[i] = 0;
}

// Kernel 0: blocks 0..9 -> LDS-tiled W transpose; blocks 10.. -> run detect +
// depth-bucketed scatter, w1 bf16 hi/lo pack, feats_part zero.
__global__ __launch_bounds__(256) void prep_kernel(
    const float* __restrict__ conv_w, float* __restrict__ Wt,
    const float* __restrict__ hf_w1, const float* __restrict__ hs_w1,
    short* __restrict__ bph, short* __restrict__ bpl,
    const int* __restrict__ idx_sorted, const int* __restrict__ node_depth,
    int* __restrict__ gcnt, int2* __restrict__ runlist,
    float* __restrict__ feats_part, int M)
{
    __shared__ float tl[32 * 257];
    __shared__ int hcnt[16], hbase[16];

    if (blockIdx.x < 10) {
        int d = blockIdx.x;
        int base = d * 8192;
        for (int t = threadIdx.x; t < 8192; t += 256)
            tl[(t >> 8) * 257 + (t & 255)] = conv_w[base + t];
        __syncthreads();
        for (int t = threadIdx.x; t < 8192; t += 256) {
            int o = t & 31, i = (t >> 5) & 31, k = t >> 10;
            Wt[base + t] = tl[o * 257 + i * 8 + k];
        }
        return;
    }

    if (threadIdx.x < 16) hcnt[threadIdx.x] = 0;
    __syncthreads();

    int j = (blockIdx.x - 10) * 256 + threadIdx.x;
    bool start = false;
    int d = 0, myp = 0, mypos = 0;

    if (j < M) {
        int p = idx_sorted[j] >> 3;
        start = (j == 0) || ((idx_sorted[j - 1] >> 3) != p);
        if (start) {
            d = node_depth[p];
            myp = p;
            mypos = atomicAdd(&hcnt[d], 1);
        }
    } else if (j < M + 512) {
        int jj = j - M;
        int lane = jj & 63;
        int q = jj >> 6;
        int m = q >> 2, tq = q & 3;
        int kg = lane >> 4, n0 = lane & 15, k0 = kg * 8;
        const float* __restrict__ w1 = m ? hs_w1 : hf_w1;
        #pragma unroll
        for (int i = 0; i < 8; ++i) {
            float w = w1[(k0 + i) * 64 + tq * 16 + n0];
            unsigned short hh = f2bf(w);
            bph[(q * 64 + lane) * 8 + i] = (short)hh;
            bpl[(q * 64 + lane) * 8 + i] = (short)f2bf(w - bf2f(hh));
        }
    } else if (j < M + 512 + FSLOTS * 32) {
        feats_part[j - (M + 512)] = 0.0f;
    }

    __syncthreads();
    if (threadIdx.x < 16) {
        int c = hcnt[threadIdx.x];
        if (c > 0) hbase[threadIdx.x] = atomicAdd(&gcnt[threadIdx.x * RSTRIDE], c);
    }
    __syncthreads();
    if (start) runlist[d * RCAP + hbase[d] + mypos] = make_int2(j, myp);
}

#define FMA8(TA, TB, X, WA, WB) \
    TA.x = fmaf(X, WA.x, TA.x); TA.y = fmaf(X, WA.y, TA.y); \
    TA.z = fmaf(X, WA.z, TA.z); TA.w = fmaf(X, WA.w, TA.w); \
    TB.x = fmaf(X, WB.x, TB.x); TB.y = fmaf(X, WB.y, TB.y); \
    TB.z = fmaf(X, WB.z, TB.z); TB.w = fmaf(X, WB.w, TB.w);

// Kernel 1: QUARTER-PARALLEL conv. Each wave owns 4 same-depth runs, one per
// 16-lane quarter. lane16 = og4*4+ig4: lane covers out-chans [og4*8,+8) and
// in-chans [ig4*8,+8). Steps of the 4 runs advance concurrently.
__global__ __launch_bounds__(256, 8) void conv_scan(
    const float* __restrict__ data, const float* __restrict__ Wt,
    const float* __restrict__ conv_b, const float* __restrict__ depth_weight,
    const int* __restrict__ idx_sorted, const int* __restrict__ depth_sorted,
    const int* __restrict__ gcnt, const int2* __restrict__ runlist,
    float* __restrict__ feats_part, float* __restrict__ patch, int M)
{
    __shared__ float fred[4][32];

    int w = (blockIdx.x * 256 + threadIdx.x) >> 6;
    int l = threadIdx.x & 63;
    int wv = threadIdx.x >> 6;
    int lane16 = l & 15, q = l >> 4;
    int og4 = lane16 >> 2, ig4 = lane16 & 3;
    int ob = og4 * 8;                 // output-channel base (8 chans)
    int ib = ig4 * 8;                 // input-channel base (8 chans)
    int tsrc = (l & 48) | (ig4 << 2) | og4;   // transpose lane within quarter

    int acc = 0, d = -1, chunk = 0, cnt = 0;
    #pragma unroll
    for (int dd = 0; dd < 10; ++dd) {
        int c = gcnt[dd * RSTRIDE];
        int nw = (c + 3) >> 2;
        if (d < 0 && w < acc + nw) { d = dd; chunk = w - acc; cnt = c; }
        acc += nw;
    }

    float4 pA = {0,0,0,0}, pB = {0,0,0,0};
    if (d >= 0) {
        int r0 = chunk * 4;
        bool vq = (r0 + q < cnt);
        int rq = r0 + q; if (rq >= cnt) rq = cnt - 1;
        int2 e = runlist[d * RCAP + rq];
        int t0 = e.x, p = e.y;        // quarter-uniform

        // window: lane16 covers entries [t0, t0+16) of this quarter's run
        int tw = t0 + lane16;
        int twc = tw < M ? tw : M - 1;
        int iw  = idx_sorted[twc];
        int dsw = depth_sorted[twc];
        unsigned long long mask = __ballot((tw < M) && ((iw >> 3) == p));
        int nq = __builtin_ctz(~(unsigned)((mask >> (q * 16)) & 0xFFFFull));
        int   ec  = iw & 7;
        float edw = depth_weight[dsw & 15];

        const float* __restrict__ W = Wt + d * 8192;   // [k][i][o]
        float4 biasA = *(const float4*)(conv_b + d * 32 + ob);
        float4 biasB = *(const float4*)(conv_b + d * 32 + ob + 4);

        // full matvec: T[ob..ob+7] partial over in-slice ib, all 8 cells
        float4 TA = {0,0,0,0}, TB = {0,0,0,0};
        #pragma unroll
        for (int k = 0; k < 8; ++k) {
            float4 xA = *(const float4*)(data + (size_t)p * 256 + k * 32 + ib);
            float4 xB = *(const float4*)(data + (size_t)p * 256 + k * 32 + ib + 4);
            #pragma unroll
            for (int jj = 0; jj < 8; ++jj) {
                float x = jj < 4 ? (jj == 0 ? xA.x : jj == 1 ? xA.y : jj == 2 ? xA.z : xA.w)
                                 : (jj == 4 ? xB.x : jj == 5 ? xB.y : jj == 6 ? xB.z : xB.w);
                const float4 wA = *(const float4*)(W + (k * 32 + ib + jj) * 32 + ob);
                const float4 wB = *(const float4*)(W + (k * 32 + ib + jj) * 32 + ob + 4);
                FMA8(TA, TB, x, wA, wB);
            }
        }
        red_ig4(TA, TB);

        // steps (concurrent across quarters)
        int nn = vq ? nq : 0;
        nn = max(nn, __shfl_xor(nn, 16, 64));
        nn = max(nn, __shfl_xor(nn, 32, 64));
        int nmax = nn;

        int c = __shfl(ec, q * 16 + 0, 64);
        int cprev = -1;
        float4 fpA = {0,0,0,0}, fpB = {0,0,0,0};

        for (int s = 0; s < nmax; ++s) {
            bool act = vq && (s < nq);
            float dw = __shfl(edw, q * 16 + s, 64);
            float4 fA = {TA.x + biasA.x, TA.y + biasA.y, TA.z + biasA.z, TA.w + biasA.w};
            float4 fB = {TB.x + biasB.x, TB.y + biasB.y, TB.z + biasB.z, TB.w + biasB.w};
            float m = act ? dw : 0.f;
            pA.x = fmaf(m, fA.x, pA.x); pA.y = fmaf(m, fA.y, pA.y);
            pA.z = fmaf(m, fA.z, pA.z); pA.w = fmaf(m, fA.w, pA.w);
            pB.x = fmaf(m, fB.x, pB.x); pB.y = fmaf(m, fB.y, pB.y);
            pB.z = fmaf(m, fB.z, pB.z); pB.w = fmaf(m, fB.w, pB.w);

            if (act && (s + 1 == nq) && p == 0 && c == 0 && ig4 == 0) {
                *(float4*)(patch + ob) = fA;
                *(float4*)(patch + ob + 4) = fB;
            }

            if (s + 1 < nmax) {            // wave-uniform branch
                int cn = __shfl(ec, q * 16 + s + 1, 64);
                // old value of cell c (dups are adjacent-only)
                float4 ovA, ovB;
                if (c == cprev) { ovA = fpA; ovB = fpB; }
                else {
                    ovA = *(const float4*)(data + (size_t)p * 256 + c * 32 + ob);
                    ovB = *(const float4*)(data + (size_t)p * 256 + c * 32 + ob + 4);
                }
                float4 duA = {fA.x - ovA.x, fA.y - ovA.y, fA.z - ovA.z, fA.w - ovA.w};
                float4 duB = {fB.x - ovB.x, fB.y - ovB.y, fB.z - ovB.z, fB.w - ovB.w};
                float4 uA = shfl4(duA, tsrc);         // delta at chans ib..ib+7
                float4 uB = shfl4(duB, tsrc);

                float4 aA = {0,0,0,0}, aB = {0,0,0,0};
                #pragma unroll
                for (int jj = 0; jj < 8; ++jj) {
                    float x = jj < 4 ? (jj == 0 ? uA.x : jj == 1 ? uA.y : jj == 2 ? uA.z : uA.w)
                                     : (jj == 4 ? uB.x : jj == 5 ? uB.y : jj == 6 ? uB.z : uB.w);
                    const float4 wA = *(const float4*)(W + (c * 32 + ib + jj) * 32 + ob);
                    const float4 wB = *(const float4*)(W + (c * 32 + ib + jj) * 32 + ob + 4);
                    FMA8(aA, aB, x, wA, wB);
                }
                red_ig4(aA, aB);
                TA.x += aA.x; TA.y += aA.y; TA.z += aA.z; TA.w += aA.w;
                TB.x += aB.x; TB.y += aB.y; TB.z += aB.z; TB.w += aB.w;

                fpA = fA; fpB = fB; cprev = c; c = cn;
            }
        }
    }

    // sum the 4 quarters, then block-reduce -> 32 atomics per block
    red_q(pA, pB);
    if (l < 16 && (l & 3) == 0) {
        *(float4*)(&fred[wv][ob])     = pA;
        *(float4*)(&fred[wv][ob + 4]) = pB;
    }
    __syncthreads();
    if (threadIdx.x < 32) {
        float s = fred[0][threadIdx.x] + fred[1][threadIdx.x]
                + fred[2][threadIdx.x] + fred[3][threadIdx.x];
        atomicAdd(&feats_part[(blockIdx.x & (FSLOTS - 1)) * 32 + threadIdx.x], s);
    }
}

// Kernel 2: leaf gather + both MLPs via MFMA (unchanged).
__global__ __launch_bounds__(256, 4) void mlp_kernel(
    const float* __restrict__ data, const float* __restrict__ feats_part,
    const float* __restrict__ patch, const int* __restrict__ leaf_idx,
    const short* __restrict__ bph, const short* __restrict__ bpl,
    const float* __restrict__ hf_w1, const float* __restrict__ hs_w1,
    const float* __restrict__ hf_b1, const float* __restrict__ hf_w2,
    const float* __restrict__ hf_b2, const float* __restrict__ hs_b1,
    const float* __restrict__ hs_w2, const float* __restrict__ hs_b2,
    float* __restrict__ out, int L)
{
    __shared__ float red[256];
    __shared__ float sh_fts[32];
    __shared__ float sh_fvec[128];
    __shared__ __align__(16) short sh_b[4096];

    {
        int ch = threadIdx.x & 31, g = threadIdx.x >> 5;
        float s = 0.f;
        #pragma unroll
        for (int j = 0; j < FSLOTS / 8; ++j)
            s += feats_part[(g + j * 8) * 32 + ch];
        red[threadIdx.x] = s;
        __syncthreads();
        if (threadIdx.x < 128) red[threadIdx.x] += red[threadIdx.x + 128];
        __syncthreads();
        if (threadIdx.x < 64) red[threadIdx.x] += red[threadIdx.x + 64];
        __syncthreads();
        if (threadIdx.x < 32)
            sh_fts[threadIdx.x] = red[threadIdx.x] + red[threadIdx.x + 32];
        __syncthreads();
    }

    {
        const int4* src = (const int4*)bph;
        int4* dst = (int4*)sh_b;
        for (int t = threadIdx.x; t < 512; t += 256) dst[t] = src[t];

        if (threadIdx.x < 128) {
            int m = threadIdx.x >> 6, h = threadIdx.x & 63;
            const float* __restrict__ w1 = m ? hs_w1 : hf_w1;
            float s = 0.f;
            #pragma unroll
            for (int k = 0; k < 32; ++k) s = fmaf(sh_fts[k], w1[k * 64 + h], s);
            sh_fvec[threadIdx.x] = s;
        }
        __syncthreads();
    }

    int l = threadIdx.x & 63;
    int ck = blockIdx.x * 4 + (threadIdx.x >> 6);
    int nchunks = (L + 63) >> 6;
    if (ck >= nchunks) return;
    int base = ck * 64;
    int n0 = l & 15, kg = l >> 4, k0 = kg * 8;

    float w2r[16], b1r[8];
    #pragma unroll
    for (int t = 0; t < 4; ++t) {
        int h = t * 16 + n0;
        w2r[t * 4 + 0] = hf_w2[h * 3 + 0];
        w2r[t * 4 + 1] = hf_w2[h * 3 + 1];
        w2r[t * 4 + 2] = hf_w2[h * 3 + 2];
        w2r[t * 4 + 3] = hs_w2[h];
        b1r[t]     = hf_b1[h] + sh_fvec[h];
        b1r[4 + t] = hs_b1[h] + sh_fvec[64 + h];
    }
    float b20 = hf_b2[0], b21 = hf_b2[1], b22 = hf_b2[2], b23 = hs_b2[0];

    #pragma unroll
    for (int tm = 0; tm < 4; ++tm) {
        int r  = base + tm * 16 + n0;
        int rc = r < L ? r : L - 1;
        int row = leaf_idx[rc];
        const float* __restrict__ src = (row == 0) ? patch : (data + (size_t)row * 32);
        float4 vA = *(const float4*)(src + k0);
        float4 vB = *(const float4*)(src + k0 + 4);
        float xv[8] = {vA.x, vA.y, vA.z, vA.w, vB.x, vB.y, vB.z, vB.w};
        short8 ahi;
        #pragma unroll
        for (int i = 0; i < 8; ++i) ahi[i] = (short)f2bf(xv[i]);

        f32x4 acc[8];
        bool anyPatch = __any(row == 0);
        if (!anyPatch) {
            #pragma unroll
            for (int qq = 0; qq < 8; ++qq) {
                short8 bh = *(const short8*)(sh_b + (qq * 64 + l) * 8);
                float bv = b1r[qq];
                f32x4 a = (f32x4){bv, bv, bv, bv};
                acc[qq] = __builtin_amdgcn_mfma_f32_16x16x32_bf16(ahi, bh, a, 0, 0, 0);
            }
        } else {
            short8 alo;
            #pragma unroll
            for (int i = 0; i < 8; ++i) {
                unsigned short hh = (unsigned short)ahi[i];
                alo[i] = (short)f2bf(xv[i] - bf2f(hh));
            }
            #pragma unroll
            for (int qq = 0; qq < 8; ++qq) {
                short8 bh = *(const short8*)(sh_b + (qq * 64 + l) * 8);
                short8 bl = *(const short8*)(bpl + (qq * 64 + l) * 8);
                float bv = b1r[qq];
                f32x4 a = (f32x4){bv, bv, bv, bv};
                a = __builtin_amdgcn_mfma_f32_16x16x32_bf16(ahi, bh, a, 0, 0, 0);
                a = __builtin_amdgcn_mfma_f32_16x16x32_bf16(alo, bh, a, 0, 0, 0);
                a = __builtin_amdgcn_mfma_f32_16x16x32_bf16(ahi, bl, a, 0, 0, 0);
                acc[qq] = a;
            }
        }

        float o[4][4];
        #pragma unroll
        for (int g2 = 0; g2 < 4; ++g2) {
            #pragma unroll
            for (int c = 0; c < 4; ++c) o[g2][c] = 0.f;
        }
        #pragma unroll
        for (int t = 0; t < 4; ++t) {
            #pragma unroll
            for (int reg = 0; reg < 4; ++reg) {
                float gf = gelu_fast(acc[t][reg]);
                float gs = gelu_fast(acc[4 + t][reg]);
                o[reg][0] = fmaf(gf, w2r[t * 4 + 0], o[reg][0]);
                o[reg][1] = fmaf(gf, w2r[t * 4 + 1], o[reg][1]);
                o[reg][2] = fmaf(gf, w2r[t * 4 + 2], o[reg][2]);
                o[reg][3] = fmaf(gs, w2r[t * 4 + 3], o[reg][3]);
            }
        }
        #pragma unroll
        for (int mk = 1; mk < 16; mk <<= 1) {
            #pragma unroll
            for (int reg = 0; reg < 4; ++reg) {
                #pragma unroll
                for (int c = 0; c < 4; ++c)
                    o[reg][c] += __shfl_xor(o[reg][c], mk, 64);
            }
        }
        if (n0 < 4) {
            int rL = base + tm * 16 + kg * 4 + n0;
            if (rL < L) {
                float s0 = n0 == 0 ? o[0][0] : n0 == 1 ? o[1][0] : n0 == 2 ? o[2][0] : o[3][0];
                float s1 = n0 == 0 ? o[0][1] : n0 == 1 ? o[1][1] : n0 == 2 ? o[2][1] : o[3][1];
                float s2 = n0 == 0 ? o[0][2] : n0 == 1 ? o[1][2] : n0 == 2 ? o[2][2] : o[3][2];
                float s3 = n0 == 0 ? o[0][3] : n0 == 1 ? o[1][3] : n0 == 2 ? o[2][3] : o[3][3];
                float4 res = {s0 + b20, s1 + b21, s2 + b22, s3 + b23};
                *(float4*)(out + (size_t)rL * 4) = res;
            }
        }
    }
}

extern "C" void kernel_launch(void* const* d_in, const int* in_sizes, int n_in,
                              void* d_out, int out_size, void* d_ws, size_t ws_size,
                              hipStream_t stream)
{
    const float* data         = (const float*)d_in[0];
    const float* conv_w       = (const float*)d_in[1];
    const float* conv_b       = (const float*)d_in[2];
    const float* depth_weight = (const float*)d_in[3];
    const float* hf_w1        = (const float*)d_in[4];
    const float* hf_b1        = (const float*)d_in[5];
    const float* hf_w2        = (const float*)d_in[6];
    const float* hf_b2        = (const float*)d_in[7];
    const float* hs_w1        = (const float*)d_in[8];
    const float* hs_b1        = (const float*)d_in[9];
    const float* hs_w2        = (const float*)d_in[10];
    const float* hs_b2        = (const float*)d_in[11];
    const int*   idx_sorted   = (const int*)d_in[12];
    const int*   depth_sorted = (const int*)d_in[13];
    const int*   node_depth   = (const int*)d_in[14];
    const int*   leaf_idx     = (const int*)d_in[15];

    int M = in_sizes[12];   // 30000
    int L = in_sizes[15];   // 210001
    float* out = (float*)d_out;

    float* Wt         = (float*)d_ws;
    float* patch      = Wt + WT_N;
    short* bph        = (short*)(patch + 32);
    short* bpl        = bph + 4096;
    int*   gcnt       = (int*)(bpl + 4096);
    float* feats_part = (float*)(gcnt + 10 * RSTRIDE);
    int2*  runlist    = (int2*)(feats_part + FSLOTS * 32);

    zero_kernel<<<2, 256, 0, stream>>>(gcnt);

    int nb_prep = 10 + (M + 512 + FSLOTS * 32 + 255) / 256;
    prep_kernel<<<nb_prep, 256, 0, stream>>>(
        conv_w, Wt, hf_w1, hs_w1, bph, bpl,
        idx_sorted, node_depth, gcnt, runlist, feats_part, M);

    int max_waves = (M + 3) / 4 + 10;
    conv_scan<<<(max_waves + 3) / 4, 256, 0, stream>>>(
        data, Wt, conv_b, depth_weight, idx_sorted, depth_sorted,
        gcnt, runlist, feats_part, patch, M);

    int nchunks = (L + 63) / 64;
    mlp_kernel<<<(nchunks + 3) / 4, 256, 0, stream>>>(
        data, feats_part, patch, leaf_idx, bph, bpl,
        hf_w1, hs_w1,
        hf_b1, hf_w2, hf_b2, hs_b1, hs_w2, hs_b2, out, L);
}

// Round 20
// 101.772 us; speedup vs baseline: 1.3368x; 1.3368x over previous
//
#include <hip/hip_runtime.h>
#include <hip/hip_bf16.h>
#include <math.h>

// ---------------------------------------------------------------------------
// M=30000 nodes, S=8 cells, D=32 channels, DEPTH_LIMIT=10, H=64, L=7M+1.
// 4 nodes: zero(gcnt) -> prep -> conv(4-run batched) -> mlp.
// Round-20: revert to round-18 structure (best, 57.8us); single change:
// conv __launch_bounds__(256,8) — VGPR_Count is exactly 64 (r16), so the
// old (256,4) declaration, not registers, was capping residency at 16
// waves/CU while the latency-bound chain needs overlap (occupancy was 20%).
// ---------------------------------------------------------------------------

typedef __attribute__((ext_vector_type(8))) short short8;
typedef __attribute__((ext_vector_type(4))) float f32x4;

#define WT_N 81920    // 10*32*32*8
#define RCAP 30720    // per-depth run-list capacity
#define RSTRIDE 32    // gcnt padding (ints): one counter per 128B line
#define FSLOTS 256    // feats_part rows (one 128B line each)

__device__ __forceinline__ unsigned short f2bf(float x) {
    __hip_bfloat16 h = __float2bfloat16(x);
    return *reinterpret_cast<unsigned short*>(&h);
}
__device__ __forceinline__ float bf2f(unsigned short h) {
    union { float f; unsigned u; } v; v.u = ((unsigned)h) << 16;
    return v.f;
}

__device__ __forceinline__ float4 shfl4(float4 v, int src) {
    float4 r;
    r.x = __shfl(v.x, src, 64);
    r.y = __shfl(v.y, src, 64);
    r.z = __shfl(v.z, src, 64);
    r.w = __shfl(v.w, src, 64);
    return r;
}

__device__ __forceinline__ void red_ig(float4& T) {
    #pragma unroll
    for (int m = 8; m <= 32; m <<= 1) {
        T.x += __shfl_xor(T.x, m, 64);
        T.y += __shfl_xor(T.y, m, 64);
        T.z += __shfl_xor(T.z, m, 64);
        T.w += __shfl_xor(T.w, m, 64);
    }
}

__device__ __forceinline__ float gelu_fast(float x)
{
    float e = __expf(-1.702f * x);
    return x * __builtin_amdgcn_rcpf(1.0f + e);
}

// Kernel Z: zero gcnt.
__global__ __launch_bounds__(256) void zero_kernel(int* __restrict__ dst)
{
    int i = blockIdx.x * 256 + threadIdx.x;
    if (i < 10 * RSTRIDE) dst[i] = 0;
}

// Kernel 0: blocks 0..9 -> LDS-tiled W transpose; blocks 10.. -> run detect +
// depth-bucketed scatter, w1 bf16 hi/lo pack, feats_part zero.
__global__ __launch_bounds__(256) void prep_kernel(
    const float* __restrict__ conv_w, float* __restrict__ Wt,
    const float* __restrict__ hf_w1, const float* __restrict__ hs_w1,
    short* __restrict__ bph, short* __restrict__ bpl,
    const int* __restrict__ idx_sorted, const int* __restrict__ node_depth,
    int* __restrict__ gcnt, int2* __restrict__ runlist,
    float* __restrict__ feats_part, int M)
{
    __shared__ float tl[32 * 257];
    __shared__ int hcnt[16], hbase[16];

    if (blockIdx.x < 10) {
        int d = blockIdx.x;
        int base = d * 8192;
        for (int t = threadIdx.x; t < 8192; t += 256)
            tl[(t >> 8) * 257 + (t & 255)] = conv_w[base + t];
        __syncthreads();
        for (int t = threadIdx.x; t < 8192; t += 256) {
            int o = t & 31, i = (t >> 5) & 31, k = t >> 10;
            Wt[base + t] = tl[o * 257 + i * 8 + k];
        }
        return;
    }

    if (threadIdx.x < 16) hcnt[threadIdx.x] = 0;
    __syncthreads();

    int j = (blockIdx.x - 10) * 256 + threadIdx.x;
    bool start = false;
    int d = 0, myp = 0, mypos = 0;

    if (j < M) {
        int p = idx_sorted[j] >> 3;
        start = (j == 0) || ((idx_sorted[j - 1] >> 3) != p);
        if (start) {
            d = node_depth[p];
            myp = p;
            mypos = atomicAdd(&hcnt[d], 1);
        }
    } else if (j < M + 512) {
        int jj = j - M;
        int lane = jj & 63;
        int q = jj >> 6;
        int m = q >> 2, tq = q & 3;
        int kg = lane >> 4, n0 = lane & 15, k0 = kg * 8;
        const float* __restrict__ w1 = m ? hs_w1 : hf_w1;
        #pragma unroll
        for (int i = 0; i < 8; ++i) {
            float w = w1[(k0 + i) * 64 + tq * 16 + n0];
            unsigned short hh = f2bf(w);
            bph[(q * 64 + lane) * 8 + i] = (short)hh;
            bpl[(q * 64 + lane) * 8 + i] = (short)f2bf(w - bf2f(hh));
        }
    } else if (j < M + 512 + FSLOTS * 32) {
        feats_part[j - (M + 512)] = 0.0f;
    }

    __syncthreads();
    if (threadIdx.x < 16) {
        int c = hcnt[threadIdx.x];
        if (c > 0) hbase[threadIdx.x] = atomicAdd(&gcnt[threadIdx.x * RSTRIDE], c);
    }
    __syncthreads();
    if (start) runlist[d * RCAP + hbase[d] + mypos] = make_int2(j, myp);
}

// Per-run sequential steps (inline; valid/n/p/base16 are wave-uniform).
__device__ __forceinline__ void run_steps(
    float4& T, float4& blk, float4& pfs, int ec, float edw, int base16,
    int n, int p, bool valid, const float* __restrict__ W, float4 bias,
    int og, int og8, int ig, float* __restrict__ patch)
{
    if (!valid) return;
    int c = __shfl(ec, base16, 64);
    float4 wc0 = *(const float4*)(W + (c * 32 + ig * 4 + 0) * 32 + og);
    float4 wc1 = *(const float4*)(W + (c * 32 + ig * 4 + 1) * 32 + og);
    float4 wc2 = *(const float4*)(W + (c * 32 + ig * 4 + 2) * 32 + og);
    float4 wc3 = *(const float4*)(W + (c * 32 + ig * 4 + 3) * 32 + og);

    for (int s = 0;; ++s) {
        float dw = __shfl(edw, base16 + s, 64);
        float4 feat = {T.x + bias.x, T.y + bias.y, T.z + bias.z, T.w + bias.w};
        pfs.x = fmaf(dw, feat.x, pfs.x); pfs.y = fmaf(dw, feat.y, pfs.y);
        pfs.z = fmaf(dw, feat.z, pfs.z); pfs.w = fmaf(dw, feat.w, pfs.w);

        if (s + 1 == n) {
            if (p == 0 && c == 0 && ig == 0)
                *(float4*)(patch + og) = feat;
            return;
        }

        int cn = __shfl(ec, base16 + s + 1, 64);
        float4 nw0 = *(const float4*)(W + (cn * 32 + ig * 4 + 0) * 32 + og);
        float4 nw1 = *(const float4*)(W + (cn * 32 + ig * 4 + 1) * 32 + og);
        float4 nw2 = *(const float4*)(W + (cn * 32 + ig * 4 + 2) * 32 + og);
        float4 nw3 = *(const float4*)(W + (cn * 32 + ig * 4 + 3) * 32 + og);

        float4 ov = shfl4(blk, c * 8 + og8);
        float4 du = {feat.x - ov.x, feat.y - ov.y, feat.z - ov.z, feat.w - ov.w};
        if (ig == c) blk = feat;                 // scatter write into tree
        float4 u = shfl4(du, og8 * 8 + ig);      // delta at chans ig*4..+3

        float4 a4;
        a4.x = u.x * wc0.x; a4.y = u.x * wc0.y;
        a4.z = u.x * wc0.z; a4.w = u.x * wc0.w;
        a4.x = fmaf(u.y, wc1.x, a4.x); a4.y = fmaf(u.y, wc1.y, a4.y);
        a4.z = fmaf(u.y, wc1.z, a4.z); a4.w = fmaf(u.y, wc1.w, a4.w);
        a4.x = fmaf(u.z, wc2.x, a4.x); a4.y = fmaf(u.z, wc2.y, a4.y);
        a4.z = fmaf(u.z, wc2.z, a4.z); a4.w = fmaf(u.z, wc2.w, a4.w);
        a4.x = fmaf(u.w, wc3.x, a4.x); a4.y = fmaf(u.w, wc3.y, a4.y);
        a4.z = fmaf(u.w, wc3.z, a4.z); a4.w = fmaf(u.w, wc3.w, a4.w);
        red_ig(a4);
        T.x += a4.x; T.y += a4.y; T.z += a4.z; T.w += a4.w;

        c = cn;
        wc0 = nw0; wc1 = nw1; wc2 = nw2; wc3 = nw3;
    }
}

#define FMA16(T, X) \
    T.x = fmaf(X.x, w0.x, T.x); T.y = fmaf(X.x, w0.y, T.y); \
    T.z = fmaf(X.x, w0.z, T.z); T.w = fmaf(X.x, w0.w, T.w); \
    T.x = fmaf(X.y, w1.x, T.x); T.y = fmaf(X.y, w1.y, T.y); \
    T.z = fmaf(X.y, w1.z, T.z); T.w = fmaf(X.y, w1.w, T.w); \
    T.x = fmaf(X.z, w2.x, T.x); T.y = fmaf(X.z, w2.y, T.y); \
    T.z = fmaf(X.z, w2.z, T.z); T.w = fmaf(X.z, w2.w, T.w); \
    T.x = fmaf(X.w, w3.x, T.x); T.y = fmaf(X.w, w3.y, T.y); \
    T.z = fmaf(X.w, w3.z, T.z); T.w = fmaf(X.w, w3.w, T.w);

// Kernel 1: one wave per 4 SAME-DEPTH runs; batched matvec (direct x loads);
// block-reduced feats atomics. launch_bounds(256,8): VGPR=64 fits 8 blk/CU.
__global__ __launch_bounds__(256, 8) void conv_scan(
    const float* __restrict__ data, const float* __restrict__ Wt,
    const float* __restrict__ conv_b, const float* __restrict__ depth_weight,
    const int* __restrict__ idx_sorted, const int* __restrict__ depth_sorted,
    const int* __restrict__ gcnt, const int2* __restrict__ runlist,
    float* __restrict__ feats_part, float* __restrict__ patch, int M)
{
    __shared__ float fred[4][32];

    int w = (blockIdx.x * 256 + threadIdx.x) >> 6;
    int l = threadIdx.x & 63;
    int wv = threadIdx.x >> 6;
    int og8 = l & 7, og = og8 * 4, ig = l >> 3;
    int q = l >> 4;

    int acc = 0, d = -1, chunk = 0, cnt = 0;
    #pragma unroll
    for (int dd = 0; dd < 10; ++dd) {
        int c = gcnt[dd * RSTRIDE];
        int nw = (c + 3) >> 2;
        if (d < 0 && w < acc + nw) { d = dd; chunk = w - acc; cnt = c; }
        acc += nw;
    }

    float4 pfs = {0, 0, 0, 0};
    if (d >= 0) {
        int r0 = chunk * 4;
        int rq = r0 + q; if (rq >= cnt) rq = cnt - 1;
        int2 e = runlist[d * RCAP + rq];
        int t0l = e.x, pl = e.y;

        int wl = l & 15;
        int tw = t0l + wl;
        int twc = tw < M ? tw : M - 1;
        int iw  = idx_sorted[twc];
        int dsw = depth_sorted[twc];
        unsigned long long mask = __ballot((tw < M) && ((iw >> 3) == pl));
        int   ec  = iw & 7;
        float edw = depth_weight[dsw & 15];

        const float* __restrict__ W = Wt + d * 8192;    // [k][i][o]
        const float4 bias = *(const float4*)(conv_b + d * 32 + og);

        int p0 = __shfl(pl, 0, 64),  p1 = __shfl(pl, 16, 64),
            p2 = __shfl(pl, 32, 64), p3 = __shfl(pl, 48, 64);
        int n0 = __builtin_ctz(~(unsigned)( mask        & 0xFFFFull));
        int n1 = __builtin_ctz(~(unsigned)((mask >> 16) & 0xFFFFull));
        int n2 = __builtin_ctz(~(unsigned)((mask >> 32) & 0xFFFFull));
        int n3 = __builtin_ctz(~(unsigned)((mask >> 48) & 0xFFFFull));
        bool v0 = (r0 + 0 < cnt), v1 = (r0 + 1 < cnt),
             v2 = (r0 + 2 < cnt), v3 = (r0 + 3 < cnt);

        // block rows for the step phase (one float4/lane per run)
        float4 B0 = *(const float4*)(data + (size_t)p0 * 256 + ig * 32 + og);
        float4 B1 = *(const float4*)(data + (size_t)p1 * 256 + ig * 32 + og);
        float4 B2 = *(const float4*)(data + (size_t)p2 * 256 + ig * 32 + og);
        float4 B3 = *(const float4*)(data + (size_t)p3 * 256 + ig * 32 + og);

        // batched full matvec; x loaded directly (no cross-lane broadcast)
        float4 T0 = {0,0,0,0}, T1 = {0,0,0,0}, T2 = {0,0,0,0}, T3 = {0,0,0,0};
        #pragma unroll
        for (int k = 0; k < 8; ++k) {
            const float4 w0 = *(const float4*)(W + (k * 32 + ig * 4 + 0) * 32 + og);
            const float4 w1 = *(const float4*)(W + (k * 32 + ig * 4 + 1) * 32 + og);
            const float4 w2 = *(const float4*)(W + (k * 32 + ig * 4 + 2) * 32 + og);
            const float4 w3 = *(const float4*)(W + (k * 32 + ig * 4 + 3) * 32 + og);
            float4 x0 = *(const float4*)(data + (size_t)p0 * 256 + k * 32 + ig * 4);
            float4 x1 = *(const float4*)(data + (size_t)p1 * 256 + k * 32 + ig * 4);
            float4 x2 = *(const float4*)(data + (size_t)p2 * 256 + k * 32 + ig * 4);
            float4 x3 = *(const float4*)(data + (size_t)p3 * 256 + k * 32 + ig * 4);
            FMA16(T0, x0); FMA16(T1, x1); FMA16(T2, x2); FMA16(T3, x3);
        }
        red_ig(T0); red_ig(T1); red_ig(T2); red_ig(T3);

        run_steps(T0, B0, pfs, ec, edw,  0, n0, p0, v0, W, bias, og, og8, ig, patch);
        run_steps(T1, B1, pfs, ec, edw, 16, n1, p1, v1, W, bias, og, og8, ig, patch);
        run_steps(T2, B2, pfs, ec, edw, 32, n2, p2, v2, W, bias, og, og8, ig, patch);
        run_steps(T3, B3, pfs, ec, edw, 48, n3, p3, v3, W, bias, og, og8, ig, patch);
    }

    // block-level pf reduction -> 32 atomics per block onto FSLOTS rows
    if (ig == 0) {
        fred[wv][og + 0] = pfs.x;
        fred[wv][og + 1] = pfs.y;
        fred[wv][og + 2] = pfs.z;
        fred[wv][og + 3] = pfs.w;
    }
    __syncthreads();
    if (threadIdx.x < 32) {
        float s = fred[0][threadIdx.x] + fred[1][threadIdx.x]
                + fred[2][threadIdx.x] + fred[3][threadIdx.x];
        atomicAdd(&feats_part[(blockIdx.x & (FSLOTS - 1)) * 32 + threadIdx.x], s);
    }
}

// Kernel 2: leaf gather + both MLPs via MFMA (round-15 version).
__global__ __launch_bounds__(256, 4) void mlp_kernel(
    const float* __restrict__ data, const float* __restrict__ feats_part,
    const float* __restrict__ patch, const int* __restrict__ leaf_idx,
    const short* __restrict__ bph, const short* __restrict__ bpl,
    const float* __restrict__ hf_w1, const float* __restrict__ hs_w1,
    const float* __restrict__ hf_b1, const float* __restrict__ hf_w2,
    const float* __restrict__ hf_b2, const float* __restrict__ hs_b1,
    const float* __restrict__ hs_w2, const float* __restrict__ hs_b2,
    float* __restrict__ out, int L)
{
    __shared__ float red[256];
    __shared__ float sh_fts[32];
    __shared__ float sh_fvec[128];
    __shared__ __align__(16) short sh_b[4096];

    {
        int ch = threadIdx.x & 31, g = threadIdx.x >> 5;
        float s = 0.f;
        #pragma unroll
        for (int j = 0; j < FSLOTS / 8; ++j)
            s += feats_part[(g + j * 8) * 32 + ch];
        red[threadIdx.x] = s;
        __syncthreads();
        if (threadIdx.x < 128) red[threadIdx.x] += red[threadIdx.x + 128];
        __syncthreads();
        if (threadIdx.x < 64) red[threadIdx.x] += red[threadIdx.x + 64];
        __syncthreads();
        if (threadIdx.x < 32)
            sh_fts[threadIdx.x] = red[threadIdx.x] + red[threadIdx.x + 32];
        __syncthreads();
    }

    {
        const int4* src = (const int4*)bph;
        int4* dst = (int4*)sh_b;
        for (int t = threadIdx.x; t < 512; t += 256) dst[t] = src[t];

        if (threadIdx.x < 128) {
            int m = threadIdx.x >> 6, h = threadIdx.x & 63;
            const float* __restrict__ w1 = m ? hs_w1 : hf_w1;
            float s = 0.f;
            #pragma unroll
            for (int k = 0; k < 32; ++k) s = fmaf(sh_fts[k], w1[k * 64 + h], s);
            sh_fvec[threadIdx.x] = s;
        }
        __syncthreads();
    }

    int l = threadIdx.x & 63;
    int ck = blockIdx.x * 4 + (threadIdx.x >> 6);
    int nchunks = (L + 63) >> 6;
    if (ck >= nchunks) return;
    int base = ck * 64;
    int n0 = l & 15, kg = l >> 4, k0 = kg * 8;

    float w2r[16], b1r[8];
    #pragma unroll
    for (int t = 0; t < 4; ++t) {
        int h = t * 16 + n0;
        w2r[t * 4 + 0] = hf_w2[h * 3 + 0];
        w2r[t * 4 + 1] = hf_w2[h * 3 + 1];
        w2r[t * 4 + 2] = hf_w2[h * 3 + 2];
        w2r[t * 4 + 3] = hs_w2[h];
        b1r[t]     = hf_b1[h] + sh_fvec[h];
        b1r[4 + t] = hs_b1[h] + sh_fvec[64 + h];
    }
    float b20 = hf_b2[0], b21 = hf_b2[1], b22 = hf_b2[2], b23 = hs_b2[0];

    #pragma unroll
    for (int tm = 0; tm < 4; ++tm) {
        int r  = base + tm * 16 + n0;
        int rc = r < L ? r : L - 1;
        int row = leaf_idx[rc];
        const float* __restrict__ src = (row == 0) ? patch : (data + (size_t)row * 32);
        float4 vA = *(const float4*)(src + k0);
        float4 vB = *(const float4*)(src + k0 + 4);
        float xv[8] = {vA.x, vA.y, vA.z, vA.w, vB.x, vB.y, vB.z, vB.w};
        short8 ahi;
        #pragma unroll
        for (int i = 0; i < 8; ++i) ahi[i] = (short)f2bf(xv[i]);

        f32x4 acc[8];
        bool anyPatch = __any(row == 0);
        if (!anyPatch) {
            #pragma unroll
            for (int qq = 0; qq < 8; ++qq) {
                short8 bh = *(const short8*)(sh_b + (qq * 64 + l) * 8);
                float bv = b1r[qq];
                f32x4 a = (f32x4){bv, bv, bv, bv};
                acc[qq] = __builtin_amdgcn_mfma_f32_16x16x32_bf16(ahi, bh, a, 0, 0, 0);
            }
        } else {
            short8 alo;
            #pragma unroll
            for (int i = 0; i < 8; ++i) {
                unsigned short hh = (unsigned short)ahi[i];
                alo[i] = (short)f2bf(xv[i] - bf2f(hh));
            }
            #pragma unroll
            for (int qq = 0; qq < 8; ++qq) {
                short8 bh = *(const short8*)(sh_b + (qq * 64 + l) * 8);
                short8 bl = *(const short8*)(bpl + (qq * 64 + l) * 8);
                float bv = b1r[qq];
                f32x4 a = (f32x4){bv, bv, bv, bv};
                a = __builtin_amdgcn_mfma_f32_16x16x32_bf16(ahi, bh, a, 0, 0, 0);
                a = __builtin_amdgcn_mfma_f32_16x16x32_bf16(alo, bh, a, 0, 0, 0);
                a = __builtin_amdgcn_mfma_f32_16x16x32_bf16(ahi, bl, a, 0, 0, 0);
                acc[qq] = a;
            }
        }

        float o[4][4];
        #pragma unroll
        for (int g2 = 0; g2 < 4; ++g2) {
            #pragma unroll
            for (int c = 0; c < 4; ++c) o[g2][c] = 0.f;
        }
        #pragma unroll
        for (int t = 0; t < 4; ++t) {
            #pragma unroll
            for (int reg = 0; reg < 4; ++reg) {
                float gf = gelu_fast(acc[t][reg]);
                float gs = gelu_fast(acc[4 + t][reg]);
                o[reg][0] = fmaf(gf, w2r[t * 4 + 0], o[reg][0]);
                o[reg][1] = fmaf(gf, w2r[t * 4 + 1], o[reg][1]);
                o[reg][2] = fmaf(gf, w2r[t * 4 + 2], o[reg][2]);
                o[reg][3] = fmaf(gs, w2r[t * 4 + 3], o[reg][3]);
            }
        }
        #pragma unroll
        for (int mk = 1; mk < 16; mk <<= 1) {
            #pragma unroll
            for (int reg = 0; reg < 4; ++reg) {
                #pragma unroll
                for (int c = 0; c < 4; ++c)
                    o[reg][c] += __shfl_xor(o[reg][c], mk, 64);
            }
        }
        if (n0 < 4) {
            int rL = base + tm * 16 + kg * 4 + n0;
            if (rL < L) {
                float s0 = n0 == 0 ? o[0][0] : n0 == 1 ? o[1][0] : n0 == 2 ? o[2][0] : o[3][0];
                float s1 = n0 == 0 ? o[0][1] : n0 == 1 ? o[1][1] : n0 == 2 ? o[2][1] : o[3][1];
                float s2 = n0 == 0 ? o[0][2] : n0 == 1 ? o[1][2] : n0 == 2 ? o[2][2] : o[3][2];
                float s3 = n0 == 0 ? o[0][3] : n0 == 1 ? o[1][3] : n0 == 2 ? o[2][3] : o[3][3];
                float4 res = {s0 + b20, s1 + b21, s2 + b22, s3 + b23};
                *(float4*)(out + (size_t)rL * 4) = res;
            }
        }
    }
}

extern "C" void kernel_launch(void* const* d_in, const int* in_sizes, int n_in,
                              void* d_out, int out_size, void* d_ws, size_t ws_size,
                              hipStream_t stream)
{
    const float* data         = (const float*)d_in[0];
    const float* conv_w       = (const float*)d_in[1];
    const float* conv_b       = (const float*)d_in[2];
    const float* depth_weight = (const float*)d_in[3];
    const float* hf_w1        = (const float*)d_in[4];
    const float* hf_b1        = (const float*)d_in[5];
    const float* hf_w2        = (const float*)d_in[6];
    const float* hf_b2        = (const float*)d_in[7];
    const float* hs_w1        = (const float*)d_in[8];
    const float* hs_b1        = (const float*)d_in[9];
    const float* hs_w2        = (const float*)d_in[10];
    const float* hs_b2        = (const float*)d_in[11];
    const int*   idx_sorted   = (const int*)d_in[12];
    const int*   depth_sorted = (const int*)d_in[13];
    const int*   node_depth   = (const int*)d_in[14];
    const int*   leaf_idx     = (const int*)d_in[15];

    int M = in_sizes[12];   // 30000
    int L = in_sizes[15];   // 210001
    float* out = (float*)d_out;

    float* Wt         = (float*)d_ws;
    float* patch      = Wt + WT_N;
    short* bph        = (short*)(patch + 32);
    short* bpl        = bph + 4096;
    int*   gcnt       = (int*)(bpl + 4096);
    float* feats_part = (float*)(gcnt + 10 * RSTRIDE);
    int2*  runlist    = (int2*)(feats_part + FSLOTS * 32);

    zero_kernel<<<2, 256, 0, stream>>>(gcnt);

    int nb_prep = 10 + (M + 512 + FSLOTS * 32 + 255) / 256;
    prep_kernel<<<nb_prep, 256, 0, stream>>>(
        conv_w, Wt, hf_w1, hs_w1, bph, bpl,
        idx_sorted, node_depth, gcnt, runlist, feats_part, M);

    int max_waves = (M + 3) / 4 + 10;
    conv_scan<<<(max_waves + 3) / 4, 256, 0, stream>>>(
        data, Wt, conv_b, depth_weight, idx_sorted, depth_sorted,
        gcnt, runlist, feats_part, patch, M);

    int nchunks = (L + 63) / 64;
    mlp_kernel<<<(nchunks + 3) / 4, 256, 0, stream>>>(
        data, feats_part, patch, leaf_idx, bph, bpl,
        hf_w1, hs_w1,
        hf_b1, hf_w2, hf_b2, hs_b1, hs_w2, hs_b2, out, L);
}

// Round 21
// 61.354 us; speedup vs baseline: 2.2174x; 1.6588x over previous
//
#include <hip/hip_runtime.h>
#include <hip/hip_bf16.h>
#include <math.h>

// ---------------------------------------------------------------------------
// M=30000 nodes, S=8 cells, D=32 channels, DEPTH_LIMIT=10, H=64, L=7M+1.
// 4 nodes: zero(gcnt) -> prep -> conv(4-run batched) -> mlp.
// Round-21 (base = round-18, best 57.8us):
//  * prep computes run length n (<=9), packs it into runlist entries, and
//    splits each depth bucket into n==1 (front) / n>=2 (back) segments.
//  * conv merges the 4 runs' step loops into ONE loop (steps = max n, not
//    sum) with predicated, straight-line updates in two pairs -> the four
//    independent chains interleave and hide each other's latency without
//    raising issue count (r19 lesson). n==1 waves skip updates entirely.
// ---------------------------------------------------------------------------

typedef __attribute__((ext_vector_type(8))) short short8;
typedef __attribute__((ext_vector_type(4))) float f32x4;

#define WT_N 81920    // 10*32*32*8
#define RCAP 30720    // per-depth run-list capacity
#define RSTRIDE 32    // gcnt padding (ints): one 128B line per depth
#define FSLOTS 256    // feats_part rows (one 128B line each)

__device__ __forceinline__ unsigned short f2bf(float x) {
    __hip_bfloat16 h = __float2bfloat16(x);
    return *reinterpret_cast<unsigned short*>(&h);
}
__device__ __forceinline__ float bf2f(unsigned short h) {
    union { float f; unsigned u; } v; v.u = ((unsigned)h) << 16;
    return v.f;
}

__device__ __forceinline__ float4 shfl4(float4 v, int src) {
    float4 r;
    r.x = __shfl(v.x, src, 64);
    r.y = __shfl(v.y, src, 64);
    r.z = __shfl(v.z, src, 64);
    r.w = __shfl(v.w, src, 64);
    return r;
}

__device__ __forceinline__ void red_ig(float4& T) {
    #pragma unroll
    for (int m = 8; m <= 32; m <<= 1) {
        T.x += __shfl_xor(T.x, m, 64);
        T.y += __shfl_xor(T.y, m, 64);
        T.z += __shfl_xor(T.z, m, 64);
        T.w += __shfl_xor(T.w, m, 64);
    }
}

__device__ __forceinline__ float gelu_fast(float x)
{
    float e = __expf(-1.702f * x);
    return x * __builtin_amdgcn_rcpf(1.0f + e);
}

// Kernel Z: zero gcnt (both segment counters live inside the padded lines).
__global__ __launch_bounds__(256) void zero_kernel(int* __restrict__ dst)
{
    int i = blockIdx.x * 256 + threadIdx.x;
    if (i < 10 * RSTRIDE) dst[i] = 0;
}

// Kernel 0: blocks 0..9 -> LDS-tiled W transpose; blocks 10.. -> run detect
// (with n scan), two-segment depth-bucketed scatter, w1 pack, feats zero.
__global__ __launch_bounds__(256) void prep_kernel(
    const float* __restrict__ conv_w, float* __restrict__ Wt,
    const float* __restrict__ hf_w1, const float* __restrict__ hs_w1,
    short* __restrict__ bph, short* __restrict__ bpl,
    const int* __restrict__ idx_sorted, const int* __restrict__ node_depth,
    int* __restrict__ gcnt, int2* __restrict__ runlist,
    float* __restrict__ feats_part, int M)
{
    __shared__ float tl[32 * 257];
    __shared__ int hcnt[32], hbase[32];

    if (blockIdx.x < 10) {
        int d = blockIdx.x;
        int base = d * 8192;
        for (int t = threadIdx.x; t < 8192; t += 256)
            tl[(t >> 8) * 257 + (t & 255)] = conv_w[base + t];
        __syncthreads();
        for (int t = threadIdx.x; t < 8192; t += 256) {
            int o = t & 31, i = (t >> 5) & 31, k = t >> 10;
            Wt[base + t] = tl[o * 257 + i * 8 + k];
        }
        return;
    }

    if (threadIdx.x < 32) hcnt[threadIdx.x] = 0;
    __syncthreads();

    int j = (blockIdx.x - 10) * 256 + threadIdx.x;
    bool start = false;
    int d = 0, myp = 0, myn = 1, seg = 0, mypos = 0;

    if (j < M) {
        int p = idx_sorted[j] >> 3;
        start = (j == 0) || ((idx_sorted[j - 1] >> 3) != p);
        if (start) {
            int nn = 1;
            while (nn < 9 && j + nn < M && (idx_sorted[j + nn] >> 3) == p) ++nn;
            d = node_depth[p];
            myp = p;
            myn = nn;
            seg = (nn == 1) ? 0 : 1;
            mypos = atomicAdd(&hcnt[d * 2 + seg], 1);
        }
    } else if (j < M + 512) {
        int jj = j - M;
        int lane = jj & 63;
        int q = jj >> 6;
        int m = q >> 2, tq = q & 3;
        int kg = lane >> 4, n0 = lane & 15, k0 = kg * 8;
        const float* __restrict__ w1 = m ? hs_w1 : hf_w1;
        #pragma unroll
        for (int i = 0; i < 8; ++i) {
            float w = w1[(k0 + i) * 64 + tq * 16 + n0];
            unsigned short hh = f2bf(w);
            bph[(q * 64 + lane) * 8 + i] = (short)hh;
            bpl[(q * 64 + lane) * 8 + i] = (short)f2bf(w - bf2f(hh));
        }
    } else if (j < M + 512 + FSLOTS * 32) {
        feats_part[j - (M + 512)] = 0.0f;
    }

    __syncthreads();
    if (threadIdx.x < 20) {
        int c = hcnt[threadIdx.x];
        if (c > 0)
            hbase[threadIdx.x] =
                atomicAdd(&gcnt[(threadIdx.x >> 1) * RSTRIDE + (threadIdx.x & 1)], c);
    }
    __syncthreads();
    if (start) {
        int b = hbase[d * 2 + seg] + mypos;
        int idx = (seg == 0) ? b : (RCAP - 1 - b);
        runlist[d * RCAP + idx] = make_int2(j | (myn << 16), myp);
    }
}

#define FMA16(T, X) \
    T.x = fmaf(X.x, w0.x, T.x); T.y = fmaf(X.x, w0.y, T.y); \
    T.z = fmaf(X.x, w0.z, T.z); T.w = fmaf(X.x, w0.w, T.w); \
    T.x = fmaf(X.y, w1.x, T.x); T.y = fmaf(X.y, w1.y, T.y); \
    T.z = fmaf(X.y, w1.z, T.z); T.w = fmaf(X.y, w1.w, T.w); \
    T.x = fmaf(X.z, w2.x, T.x); T.y = fmaf(X.z, w2.y, T.y); \
    T.z = fmaf(X.z, w2.z, T.z); T.w = fmaf(X.z, w2.w, T.w); \
    T.x = fmaf(X.w, w3.x, T.x); T.y = fmaf(X.w, w3.y, T.y); \
    T.z = fmaf(X.w, w3.z, T.z); T.w = fmaf(X.w, w3.w, T.w);

// One run's predicated update inside the merged loop (scoped W names).
#define RUN_UPD(Tj, Bj, fj, cj, cnj, uj) \
    { \
        const float4 w0 = *(const float4*)(W + (cj * 32 + ig * 4 + 0) * 32 + og); \
        const float4 w1 = *(const float4*)(W + (cj * 32 + ig * 4 + 1) * 32 + og); \
        const float4 w2 = *(const float4*)(W + (cj * 32 + ig * 4 + 2) * 32 + og); \
        const float4 w3 = *(const float4*)(W + (cj * 32 + ig * 4 + 3) * 32 + og); \
        float4 ov = shfl4(Bj, cj * 8 + og8); \
        float gg = uj ? 1.f : 0.f; \
        float4 du = {(fj.x - ov.x) * gg, (fj.y - ov.y) * gg, \
                     (fj.z - ov.z) * gg, (fj.w - ov.w) * gg}; \
        if (uj && ig == cj) Bj = fj; \
        float4 ub = shfl4(du, og8 * 8 + ig); \
        float4 a4 = {0.f, 0.f, 0.f, 0.f}; \
        FMA16(a4, ub); \
        red_ig(a4); \
        Tj.x += a4.x; Tj.y += a4.y; Tj.z += a4.z; Tj.w += a4.w; \
        cj = uj ? cnj : cj; \
    }

// Kernel 1: one wave per 4 SAME-DEPTH runs; batched matvec; MERGED step loop
// (steps advance concurrently across the 4 runs; predicated; 2+2 pairing).
__global__ __launch_bounds__(256, 4) void conv_scan(
    const float* __restrict__ data, const float* __restrict__ Wt,
    const float* __restrict__ conv_b, const float* __restrict__ depth_weight,
    const int* __restrict__ idx_sorted, const int* __restrict__ depth_sorted,
    const int* __restrict__ gcnt, const int2* __restrict__ runlist,
    float* __restrict__ feats_part, float* __restrict__ patch, int M)
{
    __shared__ float fred[4][32];

    int w = (blockIdx.x * 256 + threadIdx.x) >> 6;
    int l = threadIdx.x & 63;
    int wv = threadIdx.x >> 6;
    int og8 = l & 7, og = og8 * 4, ig = l >> 3;
    int q = l >> 4;

    int acc = 0, d = -1, chunk = 0, cA = 0, cB = 0;
    #pragma unroll
    for (int dd = 0; dd < 10; ++dd) {
        int a = gcnt[dd * RSTRIDE];
        int b = gcnt[dd * RSTRIDE + 1];
        int nw = (a + b + 3) >> 2;
        if (d < 0 && w < acc + nw) { d = dd; chunk = w - acc; cA = a; cB = b; }
        acc += nw;
    }

    float4 pfs = {0, 0, 0, 0};
    if (d >= 0) {
        int slots = cA + cB;
        int r0 = chunk * 4;
        int rr = r0 + q;
        if (rr >= slots) rr = slots - 1;
        int idx = (rr < cA) ? rr : (RCAP - 1 - (rr - cA));
        int2 e = runlist[d * RCAP + idx];
        int t0l = e.x & 0xFFFF;
        int nlq = (e.x >> 16) & 15;
        int pl  = e.y;

        // window: quarter q's lanes (l&15) cover idx/depth_sorted[t0..t0+15]
        int wl = l & 15;
        int tw = t0l + wl;
        int twc = tw < M ? tw : M - 1;
        int iw  = idx_sorted[twc];
        int dsw = depth_sorted[twc];
        int   ec  = iw & 7;
        float edw = depth_weight[dsw & 15];

        const float* __restrict__ W = Wt + d * 8192;    // [k][i][o]
        const float4 bias = *(const float4*)(conv_b + d * 32 + og);

        int p0 = __shfl(pl, 0, 64),  p1 = __shfl(pl, 16, 64),
            p2 = __shfl(pl, 32, 64), p3 = __shfl(pl, 48, 64);
        int e0 = (r0 + 0 < slots) ? __shfl(nlq, 0, 64)  : 0;
        int e1 = (r0 + 1 < slots) ? __shfl(nlq, 16, 64) : 0;
        int e2 = (r0 + 2 < slots) ? __shfl(nlq, 32, 64) : 0;
        int e3 = (r0 + 3 < slots) ? __shfl(nlq, 48, 64) : 0;
        int nmax = max(max(e0, e1), max(e2, e3));

        // block rows for the step phase (one float4/lane per run)
        float4 B0 = *(const float4*)(data + (size_t)p0 * 256 + ig * 32 + og);
        float4 B1 = *(const float4*)(data + (size_t)p1 * 256 + ig * 32 + og);
        float4 B2 = *(const float4*)(data + (size_t)p2 * 256 + ig * 32 + og);
        float4 B3 = *(const float4*)(data + (size_t)p3 * 256 + ig * 32 + og);

        // batched full matvec; x loaded directly (no cross-lane broadcast)
        float4 T0 = {0,0,0,0}, T1 = {0,0,0,0}, T2 = {0,0,0,0}, T3 = {0,0,0,0};
        #pragma unroll
        for (int k = 0; k < 8; ++k) {
            const float4 w0 = *(const float4*)(W + (k * 32 + ig * 4 + 0) * 32 + og);
            const float4 w1 = *(const float4*)(W + (k * 32 + ig * 4 + 1) * 32 + og);
            const float4 w2 = *(const float4*)(W + (k * 32 + ig * 4 + 2) * 32 + og);
            const float4 w3 = *(const float4*)(W + (k * 32 + ig * 4 + 3) * 32 + og);
            float4 x0 = *(const float4*)(data + (size_t)p0 * 256 + k * 32 + ig * 4);
            float4 x1 = *(const float4*)(data + (size_t)p1 * 256 + k * 32 + ig * 4);
            float4 x2 = *(const float4*)(data + (size_t)p2 * 256 + k * 32 + ig * 4);
            float4 x3 = *(const float4*)(data + (size_t)p3 * 256 + k * 32 + ig * 4);
            FMA16(T0, x0); FMA16(T1, x1); FMA16(T2, x2); FMA16(T3, x3);
        }
        red_ig(T0); red_ig(T1); red_ig(T2); red_ig(T3);

        int c0 = __shfl(ec, 0, 64),  c1 = __shfl(ec, 16, 64),
            c2 = __shfl(ec, 32, 64), c3 = __shfl(ec, 48, 64);

        // MERGED step loop: all 4 runs advance together (nmax iterations)
        for (int s = 0; s < nmax; ++s) {
            float dw0 = __shfl(edw, 0 + s, 64);
            float dw1 = __shfl(edw, 16 + s, 64);
            float dw2 = __shfl(edw, 32 + s, 64);
            float dw3 = __shfl(edw, 48 + s, 64);
            float m0 = (s < e0) ? dw0 : 0.f;
            float m1 = (s < e1) ? dw1 : 0.f;
            float m2 = (s < e2) ? dw2 : 0.f;
            float m3 = (s < e3) ? dw3 : 0.f;

            float4 f0 = {T0.x + bias.x, T0.y + bias.y, T0.z + bias.z, T0.w + bias.w};
            float4 f1 = {T1.x + bias.x, T1.y + bias.y, T1.z + bias.z, T1.w + bias.w};
            float4 f2 = {T2.x + bias.x, T2.y + bias.y, T2.z + bias.z, T2.w + bias.w};
            float4 f3 = {T3.x + bias.x, T3.y + bias.y, T3.z + bias.z, T3.w + bias.w};

            pfs.x = fmaf(m0, f0.x, fmaf(m1, f1.x, fmaf(m2, f2.x, fmaf(m3, f3.x, pfs.x))));
            pfs.y = fmaf(m0, f0.y, fmaf(m1, f1.y, fmaf(m2, f2.y, fmaf(m3, f3.y, pfs.y))));
            pfs.z = fmaf(m0, f0.z, fmaf(m1, f1.z, fmaf(m2, f2.z, fmaf(m3, f3.z, pfs.z))));
            pfs.w = fmaf(m0, f0.w, fmaf(m1, f1.w, fmaf(m2, f2.w, fmaf(m3, f3.w, pfs.w))));

            if (ig == 0) {   // final flat-row-0 patch (p==0 run only)
                if (s + 1 == e0 && p0 == 0 && c0 == 0) *(float4*)(patch + og) = f0;
                if (s + 1 == e1 && p1 == 0 && c1 == 0) *(float4*)(patch + og) = f1;
                if (s + 1 == e2 && p2 == 0 && c2 == 0) *(float4*)(patch + og) = f2;
                if (s + 1 == e3 && p3 == 0 && c3 == 0) *(float4*)(patch + og) = f3;
            }

            bool u0 = (s + 1 < e0), u1 = (s + 1 < e1),
                 u2 = (s + 1 < e2), u3 = (s + 1 < e3);
            if (!(u0 | u1 | u2 | u3)) continue;   // wave-uniform

            int sn = s + 1;                        // <= 8 < 16: safe index
            int cn0 = __shfl(ec, 0 + sn, 64);
            int cn1 = __shfl(ec, 16 + sn, 64);
            int cn2 = __shfl(ec, 32 + sn, 64);
            int cn3 = __shfl(ec, 48 + sn, 64);

            // updates in two pairs (register-pressure bounded)
            RUN_UPD(T0, B0, f0, c0, cn0, u0);
            RUN_UPD(T1, B1, f1, c1, cn1, u1);
            RUN_UPD(T2, B2, f2, c2, cn2, u2);
            RUN_UPD(T3, B3, f3, c3, cn3, u3);
        }
    }

    // block-level pf reduction -> 32 atomics per block onto FSLOTS rows
    if (ig == 0) {
        fred[wv][og + 0] = pfs.x;
        fred[wv][og + 1] = pfs.y;
        fred[wv][og + 2] = pfs.z;
        fred[wv][og + 3] = pfs.w;
    }
    __syncthreads();
    if (threadIdx.x < 32) {
        float s = fred[0][threadIdx.x] + fred[1][threadIdx.x]
                + fred[2][threadIdx.x] + fred[3][threadIdx.x];
        atomicAdd(&feats_part[(blockIdx.x & (FSLOTS - 1)) * 32 + threadIdx.x], s);
    }
}

// Kernel 2: leaf gather + both MLPs via MFMA (unchanged from round 18).
__global__ __launch_bounds__(256, 4) void mlp_kernel(
    const float* __restrict__ data, const float* __restrict__ feats_part,
    const float* __restrict__ patch, const int* __restrict__ leaf_idx,
    const short* __restrict__ bph, const short* __restrict__ bpl,
    const float* __restrict__ hf_w1, const float* __restrict__ hs_w1,
    const float* __restrict__ hf_b1, const float* __restrict__ hf_w2,
    const float* __restrict__ hf_b2, const float* __restrict__ hs_b1,
    const float* __restrict__ hs_w2, const float* __restrict__ hs_b2,
    float* __restrict__ out, int L)
{
    __shared__ float red[256];
    __shared__ float sh_fts[32];
    __shared__ float sh_fvec[128];
    __shared__ __align__(16) short sh_b[4096];

    {
        int ch = threadIdx.x & 31, g = threadIdx.x >> 5;
        float s = 0.f;
        #pragma unroll
        for (int j = 0; j < FSLOTS / 8; ++j)
            s += feats_part[(g + j * 8) * 32 + ch];
        red[threadIdx.x] = s;
        __syncthreads();
        if (threadIdx.x < 128) red[threadIdx.x] += red[threadIdx.x + 128];
        __syncthreads();
        if (threadIdx.x < 64) red[threadIdx.x] += red[threadIdx.x + 64];
        __syncthreads();
        if (threadIdx.x < 32)
            sh_fts[threadIdx.x] = red[threadIdx.x] + red[threadIdx.x + 32];
        __syncthreads();
    }

    {
        const int4* src = (const int4*)bph;
        int4* dst = (int4*)sh_b;
        for (int t = threadIdx.x; t < 512; t += 256) dst[t] = src[t];

        if (threadIdx.x < 128) {
            int m = threadIdx.x >> 6, h = threadIdx.x & 63;
            const float* __restrict__ w1 = m ? hs_w1 : hf_w1;
            float s = 0.f;
            #pragma unroll
            for (int k = 0; k < 32; ++k) s = fmaf(sh_fts[k], w1[k * 64 + h], s);
            sh_fvec[threadIdx.x] = s;
        }
        __syncthreads();
    }

    int l = threadIdx.x & 63;
    int ck = blockIdx.x * 4 + (threadIdx.x >> 6);
    int nchunks = (L + 63) >> 6;
    if (ck >= nchunks) return;
    int base = ck * 64;
    int n0 = l & 15, kg = l >> 4, k0 = kg * 8;

    float w2r[16], b1r[8];
    #pragma unroll
    for (int t = 0; t < 4; ++t) {
        int h = t * 16 + n0;
        w2r[t * 4 + 0] = hf_w2[h * 3 + 0];
        w2r[t * 4 + 1] = hf_w2[h * 3 + 1];
        w2r[t * 4 + 2] = hf_w2[h * 3 + 2];
        w2r[t * 4 + 3] = hs_w2[h];
        b1r[t]     = hf_b1[h] + sh_fvec[h];
        b1r[4 + t] = hs_b1[h] + sh_fvec[64 + h];
    }
    float b20 = hf_b2[0], b21 = hf_b2[1], b22 = hf_b2[2], b23 = hs_b2[0];

    #pragma unroll
    for (int tm = 0; tm < 4; ++tm) {
        int r  = base + tm * 16 + n0;
        int rc = r < L ? r : L - 1;
        int row = leaf_idx[rc];
        const float* __restrict__ src = (row == 0) ? patch : (data + (size_t)row * 32);
        float4 vA = *(const float4*)(src + k0);
        float4 vB = *(const float4*)(src + k0 + 4);
        float xv[8] = {vA.x, vA.y, vA.z, vA.w, vB.x, vB.y, vB.z, vB.w};
        short8 ahi;
        #pragma unroll
        for (int i = 0; i < 8; ++i) ahi[i] = (short)f2bf(xv[i]);

        f32x4 acc[8];
        bool anyPatch = __any(row == 0);
        if (!anyPatch) {
            #pragma unroll
            for (int qq = 0; qq < 8; ++qq) {
                short8 bh = *(const short8*)(sh_b + (qq * 64 + l) * 8);
                float bv = b1r[qq];
                f32x4 a = (f32x4){bv, bv, bv, bv};
                acc[qq] = __builtin_amdgcn_mfma_f32_16x16x32_bf16(ahi, bh, a, 0, 0, 0);
            }
        } else {
            short8 alo;
            #pragma unroll
            for (int i = 0; i < 8; ++i) {
                unsigned short hh = (unsigned short)ahi[i];
                alo[i] = (short)f2bf(xv[i] - bf2f(hh));
            }
            #pragma unroll
            for (int qq = 0; qq < 8; ++qq) {
                short8 bh = *(const short8*)(sh_b + (qq * 64 + l) * 8);
                short8 bl = *(const short8*)(bpl + (qq * 64 + l) * 8);
                float bv = b1r[qq];
                f32x4 a = (f32x4){bv, bv, bv, bv};
                a = __builtin_amdgcn_mfma_f32_16x16x32_bf16(ahi, bh, a, 0, 0, 0);
                a = __builtin_amdgcn_mfma_f32_16x16x32_bf16(alo, bh, a, 0, 0, 0);
                a = __builtin_amdgcn_mfma_f32_16x16x32_bf16(ahi, bl, a, 0, 0, 0);
                acc[qq] = a;
            }
        }

        float o[4][4];
        #pragma unroll
        for (int g2 = 0; g2 < 4; ++g2) {
            #pragma unroll
            for (int c = 0; c < 4; ++c) o[g2][c] = 0.f;
        }
        #pragma unroll
        for (int t = 0; t < 4; ++t) {
            #pragma unroll
            for (int reg = 0; reg < 4; ++reg) {
                float gf = gelu_fast(acc[t][reg]);
                float gs = gelu_fast(acc[4 + t][reg]);
                o[reg][0] = fmaf(gf, w2r[t * 4 + 0], o[reg][0]);
                o[reg][1] = fmaf(gf, w2r[t * 4 + 1], o[reg][1]);
                o[reg][2] = fmaf(gf, w2r[t * 4 + 2], o[reg][2]);
                o[reg][3] = fmaf(gs, w2r[t * 4 + 3], o[reg][3]);
            }
        }
        #pragma unroll
        for (int mk = 1; mk < 16; mk <<= 1) {
            #pragma unroll
            for (int reg = 0; reg < 4; ++reg) {
                #pragma unroll
                for (int c = 0; c < 4; ++c)
                    o[reg][c] += __shfl_xor(o[reg][c], mk, 64);
            }
        }
        if (n0 < 4) {
            int rL = base + tm * 16 + kg * 4 + n0;
            if (rL < L) {
                float s0 = n0 == 0 ? o[0][0] : n0 == 1 ? o[1][0] : n0 == 2 ? o[2][0] : o[3][0];
                float s1 = n0 == 0 ? o[0][1] : n0 == 1 ? o[1][1] : n0 == 2 ? o[2][1] : o[3][1];
                float s2 = n0 == 0 ? o[0][2] : n0 == 1 ? o[1][2] : n0 == 2 ? o[2][2] : o[3][2];
                float s3 = n0 == 0 ? o[0][3] : n0 == 1 ? o[1][3] : n0 == 2 ? o[2][3] : o[3][3];
                float4 res = {s0 + b20, s1 + b21, s2 + b22, s3 + b23};
                *(float4*)(out + (size_t)rL * 4) = res;
            }
        }
    }
}

extern "C" void kernel_launch(void* const* d_in, const int* in_sizes, int n_in,
                              void* d_out, int out_size, void* d_ws, size_t ws_size,
                              hipStream_t stream)
{
    const float* data         = (const float*)d_in[0];
    const float* conv_w       = (const float*)d_in[1];
    const float* conv_b       = (const float*)d_in[2];
    const float* depth_weight = (const float*)d_in[3];
    const float* hf_w1        = (const float*)d_in[4];
    const float* hf_b1        = (const float*)d_in[5];
    const float* hf_w2        = (const float*)d_in[6];
    const float* hf_b2        = (const float*)d_in[7];
    const float* hs_w1        = (const float*)d_in[8];
    const float* hs_b1        = (const float*)d_in[9];
    const float* hs_w2        = (const float*)d_in[10];
    const float* hs_b2        = (const float*)d_in[11];
    const int*   idx_sorted   = (const int*)d_in[12];
    const int*   depth_sorted = (const int*)d_in[13];
    const int*   node_depth   = (const int*)d_in[14];
    const int*   leaf_idx     = (const int*)d_in[15];

    int M = in_sizes[12];   // 30000
    int L = in_sizes[15];   // 210001
    float* out = (float*)d_out;

    float* Wt         = (float*)d_ws;
    float* patch      = Wt + WT_N;
    short* bph        = (short*)(patch + 32);
    short* bpl        = bph + 4096;
    int*   gcnt       = (int*)(bpl + 4096);
    float* feats_part = (float*)(gcnt + 10 * RSTRIDE);
    int2*  runlist    = (int2*)(feats_part + FSLOTS * 32);

    zero_kernel<<<2, 256, 0, stream>>>(gcnt);

    int nb_prep = 10 + (M + 512 + FSLOTS * 32 + 255) / 256;
    prep_kernel<<<nb_prep, 256, 0, stream>>>(
        conv_w, Wt, hf_w1, hs_w1, bph, bpl,
        idx_sorted, node_depth, gcnt, runlist, feats_part, M);

    int max_waves = (M + 3) / 4 + 10;
    conv_scan<<<(max_waves + 3) / 4, 256, 0, stream>>>(
        data, Wt, conv_b, depth_weight, idx_sorted, depth_sorted,
        gcnt, runlist, feats_part, patch, M);

    int nchunks = (L + 63) / 64;
    mlp_kernel<<<(nchunks + 3) / 4, 256, 0, stream>>>(
        data, feats_part, patch, leaf_idx, bph, bpl,
        hf_w1, hs_w1,
        hf_b1, hf_w2, hf_b2, hs_b1, hs_w2, hs_b2, out, L);
}

// Round 22
// 57.856 us; speedup vs baseline: 2.3515x; 1.0605x over previous
//
#include <hip/hip_runtime.h>
#include <hip/hip_bf16.h>
#include <math.h>

// ---------------------------------------------------------------------------
// M=30000 nodes, S=8 cells, D=32 channels, DEPTH_LIMIT=10, H=64, L=7M+1.
// 4 nodes: zero(gcnt) -> prep -> conv(4-run batched) -> mlp.
// FINAL (= round-18, session best 57.8us): conv is one wave per 4 same-depth
// runs with batched matvec (direct x loads) + block-reduced feats atomics;
// mlp is single-bf16 MFMA with feats folded into the bias via fvec.
// ---------------------------------------------------------------------------

typedef __attribute__((ext_vector_type(8))) short short8;
typedef __attribute__((ext_vector_type(4))) float f32x4;

#define WT_N 81920    // 10*32*32*8
#define RCAP 30720    // per-depth run-list capacity
#define RSTRIDE 32    // gcnt padding (ints): one counter per 128B line
#define FSLOTS 256    // feats_part rows (one 128B line each)

__device__ __forceinline__ unsigned short f2bf(float x) {
    __hip_bfloat16 h = __float2bfloat16(x);
    return *reinterpret_cast<unsigned short*>(&h);
}
__device__ __forceinline__ float bf2f(unsigned short h) {
    union { float f; unsigned u; } v; v.u = ((unsigned)h) << 16;
    return v.f;
}

__device__ __forceinline__ float4 shfl4(float4 v, int src) {
    float4 r;
    r.x = __shfl(v.x, src, 64);
    r.y = __shfl(v.y, src, 64);
    r.z = __shfl(v.z, src, 64);
    r.w = __shfl(v.w, src, 64);
    return r;
}

__device__ __forceinline__ void red_ig(float4& T) {
    #pragma unroll
    for (int m = 8; m <= 32; m <<= 1) {
        T.x += __shfl_xor(T.x, m, 64);
        T.y += __shfl_xor(T.y, m, 64);
        T.z += __shfl_xor(T.z, m, 64);
        T.w += __shfl_xor(T.w, m, 64);
    }
}

__device__ __forceinline__ float gelu_fast(float x)
{
    float e = __expf(-1.702f * x);
    return x * __builtin_amdgcn_rcpf(1.0f + e);
}

// Kernel Z: zero gcnt.
__global__ __launch_bounds__(256) void zero_kernel(int* __restrict__ dst)
{
    int i = blockIdx.x * 256 + threadIdx.x;
    if (i < 10 * RSTRIDE) dst[i] = 0;
}

// Kernel 0: blocks 0..9 -> LDS-tiled W transpose; blocks 10.. -> run detect +
// depth-bucketed scatter, w1 bf16 hi/lo pack, feats_part zero.
__global__ __launch_bounds__(256) void prep_kernel(
    const float* __restrict__ conv_w, float* __restrict__ Wt,
    const float* __restrict__ hf_w1, const float* __restrict__ hs_w1,
    short* __restrict__ bph, short* __restrict__ bpl,
    const int* __restrict__ idx_sorted, const int* __restrict__ node_depth,
    int* __restrict__ gcnt, int2* __restrict__ runlist,
    float* __restrict__ feats_part, int M)
{
    __shared__ float tl[32 * 257];
    __shared__ int hcnt[16], hbase[16];

    if (blockIdx.x < 10) {
        int d = blockIdx.x;
        int base = d * 8192;
        for (int t = threadIdx.x; t < 8192; t += 256)
            tl[(t >> 8) * 257 + (t & 255)] = conv_w[base + t];
        __syncthreads();
        for (int t = threadIdx.x; t < 8192; t += 256) {
            int o = t & 31, i = (t >> 5) & 31, k = t >> 10;
            Wt[base + t] = tl[o * 257 + i * 8 + k];
        }
        return;
    }

    if (threadIdx.x < 16) hcnt[threadIdx.x] = 0;
    __syncthreads();

    int j = (blockIdx.x - 10) * 256 + threadIdx.x;
    bool start = false;
    int d = 0, myp = 0, mypos = 0;

    if (j < M) {
        int p = idx_sorted[j] >> 3;
        start = (j == 0) || ((idx_sorted[j - 1] >> 3) != p);
        if (start) {
            d = node_depth[p];
            myp = p;
            mypos = atomicAdd(&hcnt[d], 1);
        }
    } else if (j < M + 512) {
        int jj = j - M;
        int lane = jj & 63;
        int q = jj >> 6;
        int m = q >> 2, tq = q & 3;
        int kg = lane >> 4, n0 = lane & 15, k0 = kg * 8;
        const float* __restrict__ w1 = m ? hs_w1 : hf_w1;
        #pragma unroll
        for (int i = 0; i < 8; ++i) {
            float w = w1[(k0 + i) * 64 + tq * 16 + n0];
            unsigned short hh = f2bf(w);
            bph[(q * 64 + lane) * 8 + i] = (short)hh;
            bpl[(q * 64 + lane) * 8 + i] = (short)f2bf(w - bf2f(hh));
        }
    } else if (j < M + 512 + FSLOTS * 32) {
        feats_part[j - (M + 512)] = 0.0f;
    }

    __syncthreads();
    if (threadIdx.x < 16) {
        int c = hcnt[threadIdx.x];
        if (c > 0) hbase[threadIdx.x] = atomicAdd(&gcnt[threadIdx.x * RSTRIDE], c);
    }
    __syncthreads();
    if (start) runlist[d * RCAP + hbase[d] + mypos] = make_int2(j, myp);
}

// Per-run sequential steps (inline; valid/n/p/base16 are wave-uniform).
__device__ __forceinline__ void run_steps(
    float4& T, float4& blk, float4& pfs, int ec, float edw, int base16,
    int n, int p, bool valid, const float* __restrict__ W, float4 bias,
    int og, int og8, int ig, float* __restrict__ patch)
{
    if (!valid) return;
    int c = __shfl(ec, base16, 64);
    float4 wc0 = *(const float4*)(W + (c * 32 + ig * 4 + 0) * 32 + og);
    float4 wc1 = *(const float4*)(W + (c * 32 + ig * 4 + 1) * 32 + og);
    float4 wc2 = *(const float4*)(W + (c * 32 + ig * 4 + 2) * 32 + og);
    float4 wc3 = *(const float4*)(W + (c * 32 + ig * 4 + 3) * 32 + og);

    for (int s = 0;; ++s) {
        float dw = __shfl(edw, base16 + s, 64);
        float4 feat = {T.x + bias.x, T.y + bias.y, T.z + bias.z, T.w + bias.w};
        pfs.x = fmaf(dw, feat.x, pfs.x); pfs.y = fmaf(dw, feat.y, pfs.y);
        pfs.z = fmaf(dw, feat.z, pfs.z); pfs.w = fmaf(dw, feat.w, pfs.w);

        if (s + 1 == n) {
            if (p == 0 && c == 0 && ig == 0)
                *(float4*)(patch + og) = feat;
            return;
        }

        int cn = __shfl(ec, base16 + s + 1, 64);
        float4 nw0 = *(const float4*)(W + (cn * 32 + ig * 4 + 0) * 32 + og);
        float4 nw1 = *(const float4*)(W + (cn * 32 + ig * 4 + 1) * 32 + og);
        float4 nw2 = *(const float4*)(W + (cn * 32 + ig * 4 + 2) * 32 + og);
        float4 nw3 = *(const float4*)(W + (cn * 32 + ig * 4 + 3) * 32 + og);

        float4 ov = shfl4(blk, c * 8 + og8);
        float4 du = {feat.x - ov.x, feat.y - ov.y, feat.z - ov.z, feat.w - ov.w};
        if (ig == c) blk = feat;                 // scatter write into tree
        float4 u = shfl4(du, og8 * 8 + ig);      // delta at chans ig*4..+3

        float4 a4;
        a4.x = u.x * wc0.x; a4.y = u.x * wc0.y;
        a4.z = u.x * wc0.z; a4.w = u.x * wc0.w;
        a4.x = fmaf(u.y, wc1.x, a4.x); a4.y = fmaf(u.y, wc1.y, a4.y);
        a4.z = fmaf(u.y, wc1.z, a4.z); a4.w = fmaf(u.y, wc1.w, a4.w);
        a4.x = fmaf(u.z, wc2.x, a4.x); a4.y = fmaf(u.z, wc2.y, a4.y);
        a4.z = fmaf(u.z, wc2.z, a4.z); a4.w = fmaf(u.z, wc2.w, a4.w);
        a4.x = fmaf(u.w, wc3.x, a4.x); a4.y = fmaf(u.w, wc3.y, a4.y);
        a4.z = fmaf(u.w, wc3.z, a4.z); a4.w = fmaf(u.w, wc3.w, a4.w);
        red_ig(a4);
        T.x += a4.x; T.y += a4.y; T.z += a4.z; T.w += a4.w;

        c = cn;
        wc0 = nw0; wc1 = nw1; wc2 = nw2; wc3 = nw3;
    }
}

#define FMA16(T, X) \
    T.x = fmaf(X.x, w0.x, T.x); T.y = fmaf(X.x, w0.y, T.y); \
    T.z = fmaf(X.x, w0.z, T.z); T.w = fmaf(X.x, w0.w, T.w); \
    T.x = fmaf(X.y, w1.x, T.x); T.y = fmaf(X.y, w1.y, T.y); \
    T.z = fmaf(X.y, w1.z, T.z); T.w = fmaf(X.y, w1.w, T.w); \
    T.x = fmaf(X.z, w2.x, T.x); T.y = fmaf(X.z, w2.y, T.y); \
    T.z = fmaf(X.z, w2.z, T.z); T.w = fmaf(X.z, w2.w, T.w); \
    T.x = fmaf(X.w, w3.x, T.x); T.y = fmaf(X.w, w3.y, T.y); \
    T.z = fmaf(X.w, w3.z, T.z); T.w = fmaf(X.w, w3.w, T.w);

// Kernel 1: one wave per 4 SAME-DEPTH runs; batched matvec (direct x loads);
// block-reduced feats atomics.
__global__ __launch_bounds__(256, 4) void conv_scan(
    const float* __restrict__ data, const float* __restrict__ Wt,
    const float* __restrict__ conv_b, const float* __restrict__ depth_weight,
    const int* __restrict__ idx_sorted, const int* __restrict__ depth_sorted,
    const int* __restrict__ gcnt, const int2* __restrict__ runlist,
    float* __restrict__ feats_part, float* __restrict__ patch, int M)
{
    __shared__ float fred[4][32];

    int w = (blockIdx.x * 256 + threadIdx.x) >> 6;
    int l = threadIdx.x & 63;
    int wv = threadIdx.x >> 6;
    int og8 = l & 7, og = og8 * 4, ig = l >> 3;
    int q = l >> 4;

    int acc = 0, d = -1, chunk = 0, cnt = 0;
    #pragma unroll
    for (int dd = 0; dd < 10; ++dd) {
        int c = gcnt[dd * RSTRIDE];
        int nw = (c + 3) >> 2;
        if (d < 0 && w < acc + nw) { d = dd; chunk = w - acc; cnt = c; }
        acc += nw;
    }

    float4 pfs = {0, 0, 0, 0};
    if (d >= 0) {
        int r0 = chunk * 4;
        int rq = r0 + q; if (rq >= cnt) rq = cnt - 1;
        int2 e = runlist[d * RCAP + rq];
        int t0l = e.x, pl = e.y;

        int wl = l & 15;
        int tw = t0l + wl;
        int twc = tw < M ? tw : M - 1;
        int iw  = idx_sorted[twc];
        int dsw = depth_sorted[twc];
        unsigned long long mask = __ballot((tw < M) && ((iw >> 3) == pl));
        int   ec  = iw & 7;
        float edw = depth_weight[dsw & 15];

        const float* __restrict__ W = Wt + d * 8192;    // [k][i][o]
        const float4 bias = *(const float4*)(conv_b + d * 32 + og);

        int p0 = __shfl(pl, 0, 64),  p1 = __shfl(pl, 16, 64),
            p2 = __shfl(pl, 32, 64), p3 = __shfl(pl, 48, 64);
        int n0 = __builtin_ctz(~(unsigned)( mask        & 0xFFFFull));
        int n1 = __builtin_ctz(~(unsigned)((mask >> 16) & 0xFFFFull));
        int n2 = __builtin_ctz(~(unsigned)((mask >> 32) & 0xFFFFull));
        int n3 = __builtin_ctz(~(unsigned)((mask >> 48) & 0xFFFFull));
        bool v0 = (r0 + 0 < cnt), v1 = (r0 + 1 < cnt),
             v2 = (r0 + 2 < cnt), v3 = (r0 + 3 < cnt);

        // block rows for the step phase (one float4/lane per run)
        float4 B0 = *(const float4*)(data + (size_t)p0 * 256 + ig * 32 + og);
        float4 B1 = *(const float4*)(data + (size_t)p1 * 256 + ig * 32 + og);
        float4 B2 = *(const float4*)(data + (size_t)p2 * 256 + ig * 32 + og);
        float4 B3 = *(const float4*)(data + (size_t)p3 * 256 + ig * 32 + og);

        // batched full matvec; x loaded directly (no cross-lane broadcast)
        float4 T0 = {0,0,0,0}, T1 = {0,0,0,0}, T2 = {0,0,0,0}, T3 = {0,0,0,0};
        #pragma unroll
        for (int k = 0; k < 8; ++k) {
            const float4 w0 = *(const float4*)(W + (k * 32 + ig * 4 + 0) * 32 + og);
            const float4 w1 = *(const float4*)(W + (k * 32 + ig * 4 + 1) * 32 + og);
            const float4 w2 = *(const float4*)(W + (k * 32 + ig * 4 + 2) * 32 + og);
            const float4 w3 = *(const float4*)(W + (k * 32 + ig * 4 + 3) * 32 + og);
            float4 x0 = *(const float4*)(data + (size_t)p0 * 256 + k * 32 + ig * 4);
            float4 x1 = *(const float4*)(data + (size_t)p1 * 256 + k * 32 + ig * 4);
            float4 x2 = *(const float4*)(data + (size_t)p2 * 256 + k * 32 + ig * 4);
            float4 x3 = *(const float4*)(data + (size_t)p3 * 256 + k * 32 + ig * 4);
            FMA16(T0, x0); FMA16(T1, x1); FMA16(T2, x2); FMA16(T3, x3);
        }
        red_ig(T0); red_ig(T1); red_ig(T2); red_ig(T3);

        run_steps(T0, B0, pfs, ec, edw,  0, n0, p0, v0, W, bias, og, og8, ig, patch);
        run_steps(T1, B1, pfs, ec, edw, 16, n1, p1, v1, W, bias, og, og8, ig, patch);
        run_steps(T2, B2, pfs, ec, edw, 32, n2, p2, v2, W, bias, og, og8, ig, patch);
        run_steps(T3, B3, pfs, ec, edw, 48, n3, p3, v3, W, bias, og, og8, ig, patch);
    }

    // block-level pf reduction -> 32 atomics per block onto FSLOTS rows
    if (ig == 0) {
        fred[wv][og + 0] = pfs.x;
        fred[wv][og + 1] = pfs.y;
        fred[wv][og + 2] = pfs.z;
        fred[wv][og + 3] = pfs.w;
    }
    __syncthreads();
    if (threadIdx.x < 32) {
        float s = fred[0][threadIdx.x] + fred[1][threadIdx.x]
                + fred[2][threadIdx.x] + fred[3][threadIdx.x];
        atomicAdd(&feats_part[(blockIdx.x & (FSLOTS - 1)) * 32 + threadIdx.x], s);
    }
}

// Kernel 2: leaf gather + both MLPs via MFMA.
__global__ __launch_bounds__(256, 4) void mlp_kernel(
    const float* __restrict__ data, const float* __restrict__ feats_part,
    const float* __restrict__ patch, const int* __restrict__ leaf_idx,
    const short* __restrict__ bph, const short* __restrict__ bpl,
    const float* __restrict__ hf_w1, const float* __restrict__ hs_w1,
    const float* __restrict__ hf_b1, const float* __restrict__ hf_w2,
    const float* __restrict__ hf_b2, const float* __restrict__ hs_b1,
    const float* __restrict__ hs_w2, const float* __restrict__ hs_b2,
    float* __restrict__ out, int L)
{
    __shared__ float red[256];
    __shared__ float sh_fts[32];
    __shared__ float sh_fvec[128];
    __shared__ __align__(16) short sh_b[4096];

    {
        int ch = threadIdx.x & 31, g = threadIdx.x >> 5;
        float s = 0.f;
        #pragma unroll
        for (int j = 0; j < FSLOTS / 8; ++j)
            s += feats_part[(g + j * 8) * 32 + ch];
        red[threadIdx.x] = s;
        __syncthreads();
        if (threadIdx.x < 128) red[threadIdx.x] += red[threadIdx.x + 128];
        __syncthreads();
        if (threadIdx.x < 64) red[threadIdx.x] += red[threadIdx.x + 64];
        __syncthreads();
        if (threadIdx.x < 32)
            sh_fts[threadIdx.x] = red[threadIdx.x] + red[threadIdx.x + 32];
        __syncthreads();
    }

    {
        const int4* src = (const int4*)bph;
        int4* dst = (int4*)sh_b;
        for (int t = threadIdx.x; t < 512; t += 256) dst[t] = src[t];

        if (threadIdx.x < 128) {
            int m = threadIdx.x >> 6, h = threadIdx.x & 63;
            const float* __restrict__ w1 = m ? hs_w1 : hf_w1;
            float s = 0.f;
            #pragma unroll
            for (int k = 0; k < 32; ++k) s = fmaf(sh_fts[k], w1[k * 64 + h], s);
            sh_fvec[threadIdx.x] = s;
        }
        __syncthreads();
    }

    int l = threadIdx.x & 63;
    int ck = blockIdx.x * 4 + (threadIdx.x >> 6);
    int nchunks = (L + 63) >> 6;
    if (ck >= nchunks) return;
    int base = ck * 64;
    int n0 = l & 15, kg = l >> 4, k0 = kg * 8;

    float w2r[16], b1r[8];
    #pragma unroll
    for (int t = 0; t < 4; ++t) {
        int h = t * 16 + n0;
        w2r[t * 4 + 0] = hf_w2[h * 3 + 0];
        w2r[t * 4 + 1] = hf_w2[h * 3 + 1];
        w2r[t * 4 + 2] = hf_w2[h * 3 + 2];
        w2r[t * 4 + 3] = hs_w2[h];
        b1r[t]     = hf_b1[h] + sh_fvec[h];
        b1r[4 + t] = hs_b1[h] + sh_fvec[64 + h];
    }
    float b20 = hf_b2[0], b21 = hf_b2[1], b22 = hf_b2[2], b23 = hs_b2[0];

    #pragma unroll
    for (int tm = 0; tm < 4; ++tm) {
        int r  = base + tm * 16 + n0;
        int rc = r < L ? r : L - 1;
        int row = leaf_idx[rc];
        const float* __restrict__ src = (row == 0) ? patch : (data + (size_t)row * 32);
        float4 vA = *(const float4*)(src + k0);
        float4 vB = *(const float4*)(src + k0 + 4);
        float xv[8] = {vA.x, vA.y, vA.z, vA.w, vB.x, vB.y, vB.z, vB.w};
        short8 ahi;
        #pragma unroll
        for (int i = 0; i < 8; ++i) ahi[i] = (short)f2bf(xv[i]);

        f32x4 acc[8];
        bool anyPatch = __any(row == 0);
        if (!anyPatch) {
            #pragma unroll
            for (int qq = 0; qq < 8; ++qq) {
                short8 bh = *(const short8*)(sh_b + (qq * 64 + l) * 8);
                float bv = b1r[qq];
                f32x4 a = (f32x4){bv, bv, bv, bv};
                acc[qq] = __builtin_amdgcn_mfma_f32_16x16x32_bf16(ahi, bh, a, 0, 0, 0);
            }
        } else {
            short8 alo;
            #pragma unroll
            for (int i = 0; i < 8; ++i) {
                unsigned short hh = (unsigned short)ahi[i];
                alo[i] = (short)f2bf(xv[i] - bf2f(hh));
            }
            #pragma unroll
            for (int qq = 0; qq < 8; ++qq) {
                short8 bh = *(const short8*)(sh_b + (qq * 64 + l) * 8);
                short8 bl = *(const short8*)(bpl + (qq * 64 + l) * 8);
                float bv = b1r[qq];
                f32x4 a = (f32x4){bv, bv, bv, bv};
                a = __builtin_amdgcn_mfma_f32_16x16x32_bf16(ahi, bh, a, 0, 0, 0);
                a = __builtin_amdgcn_mfma_f32_16x16x32_bf16(alo, bh, a, 0, 0, 0);
                a = __builtin_amdgcn_mfma_f32_16x16x32_bf16(ahi, bl, a, 0, 0, 0);
                acc[qq] = a;
            }
        }

        float o[4][4];
        #pragma unroll
        for (int g2 = 0; g2 < 4; ++g2) {
            #pragma unroll
            for (int c = 0; c < 4; ++c) o[g2][c] = 0.f;
        }
        #pragma unroll
        for (int t = 0; t < 4; ++t) {
            #pragma unroll
            for (int reg = 0; reg < 4; ++reg) {
                float gf = gelu_fast(acc[t][reg]);
                float gs = gelu_fast(acc[4 + t][reg]);
                o[reg][0] = fmaf(gf, w2r[t * 4 + 0], o[reg][0]);
                o[reg][1] = fmaf(gf, w2r[t * 4 + 1], o[reg][1]);
                o[reg][2] = fmaf(gf, w2r[t * 4 + 2], o[reg][2]);
                o[reg][3] = fmaf(gs, w2r[t * 4 + 3], o[reg][3]);
            }
        }
        #pragma unroll
        for (int mk = 1; mk < 16; mk <<= 1) {
            #pragma unroll
            for (int reg = 0; reg < 4; ++reg) {
                #pragma unroll
                for (int c = 0; c < 4; ++c)
                    o[reg][c] += __shfl_xor(o[reg][c], mk, 64);
            }
        }
        if (n0 < 4) {
            int rL = base + tm * 16 + kg * 4 + n0;
            if (rL < L) {
                float s0 = n0 == 0 ? o[0][0] : n0 == 1 ? o[1][0] : n0 == 2 ? o[2][0] : o[3][0];
                float s1 = n0 == 0 ? o[0][1] : n0 == 1 ? o[1][1] : n0 == 2 ? o[2][1] : o[3][1];
                float s2 = n0 == 0 ? o[0][2] : n0 == 1 ? o[1][2] : n0 == 2 ? o[2][2] : o[3][2];
                float s3 = n0 == 0 ? o[0][3] : n0 == 1 ? o[1][3] : n0 == 2 ? o[2][3] : o[3][3];
                float4 res = {s0 + b20, s1 + b21, s2 + b22, s3 + b23};
                *(float4*)(out + (size_t)rL * 4) = res;
            }
        }
    }
}

extern "C" void kernel_launch(void* const* d_in, const int* in_sizes, int n_in,
                              void* d_out, int out_size, void* d_ws, size_t ws_size,
                              hipStream_t stream)
{
    const float* data         = (const float*)d_in[0];
    const float* conv_w       = (const float*)d_in[1];
    const float* conv_b       = (const float*)d_in[2];
    const float* depth_weight = (const float*)d_in[3];
    const float* hf_w1        = (const float*)d_in[4];
    const float* hf_b1        = (const float*)d_in[5];
    const float* hf_w2        = (const float*)d_in[6];
    const float* hf_b2        = (const float*)d_in[7];
    const float* hs_w1        = (const float*)d_in[8];
    const float* hs_b1        = (const float*)d_in[9];
    const float* hs_w2        = (const float*)d_in[10];
    const float* hs_b2        = (const float*)d_in[11];
    const int*   idx_sorted   = (const int*)d_in[12];
    const int*   depth_sorted = (const int*)d_in[13];
    const int*   node_depth   = (const int*)d_in[14];
    const int*   leaf_idx     = (const int*)d_in[15];

    int M = in_sizes[12];   // 30000
    int L = in_sizes[15];   // 210001
    float* out = (float*)d_out;

    float* Wt         = (float*)d_ws;
    float* patch      = Wt + WT_N;
    short* bph        = (short*)(patch + 32);
    short* bpl        = bph + 4096;
    int*   gcnt       = (int*)(bpl + 4096);
    float* feats_part = (float*)(gcnt + 10 * RSTRIDE);
    int2*  runlist    = (int2*)(feats_part + FSLOTS * 32);

    zero_kernel<<<2, 256, 0, stream>>>(gcnt);

    int nb_prep = 10 + (M + 512 + FSLOTS * 32 + 255) / 256;
    prep_kernel<<<nb_prep, 256, 0, stream>>>(
        conv_w, Wt, hf_w1, hs_w1, bph, bpl,
        idx_sorted, node_depth, gcnt, runlist, feats_part, M);

    int max_waves = (M + 3) / 4 + 10;
    conv_scan<<<(max_waves + 3) / 4, 256, 0, stream>>>(
        data, Wt, conv_b, depth_weight, idx_sorted, depth_sorted,
        gcnt, runlist, feats_part, patch, M);

    int nchunks = (L + 63) / 64;
    mlp_kernel<<<(nchunks + 3) / 4, 256, 0, stream>>>(
        data, feats_part, patch, leaf_idx, bph, bpl,
        hf_w1, hs_w1,
        hf_b1, hf_w2, hf_b2, hs_b1, hs_w2, hs_b2, out, L);
}